// Round 5
// baseline (102.741 us; speedup 1.0000x reference)
//
#include <hip/hip_runtime.h>
#include <string.h>

#define NQ 14
#define NSTATE (1 << NQ)       // 16384 amplitudes
#define NL 3
#define MAXP 12                // max table entries (init + gate passes)
#define BT 1024                // threads per block
#define NWAVES (BT / 64)
#define NEX 11                 // extra-gate combo menu size

// Lazily-permuted simulation: CNOT rings folded into GF(2) index maps, and a
// global GF(2)-linear LDS layout sigma (amp p stored at address sigma(p)).
// sigma is chosen host-side so that EVERY pass's representative space
// projects with full rank 4 onto the bank-pair bits (addr mod 16).
// This version = verified round-3 base (analytic product-state init for
// layer 0, fused measurement, vmcnt-domain param prefetch, SCALAR float2
// complex math) + span-closure extras: gates whose flip mask lies INSIDE a
// pass's rank-4 span are applied in the same LDS round trip, paired by
// their 4-bit combo with a per-thread orientation bit (sga/parw tables).
// (Round-4's packed VOP3P asm is intentionally REMOVED for bisection.)
struct PassG {
    unsigned cmb8[16];   // 0   XOR combos of pair masks, pre-shifted <<3
    unsigned R[10];      // 64  complement-basis images (tid -> rep)
    unsigned gidx[4];    // 104 basis gate table indices
    unsigned nw;         // 120 real basis gates in this pass
    unsigned epm;        // 124 extra-present mask (bit k = slot k active)
    unsigned eg[11];     // 128 sga(14b) | gidx<<16
    unsigned parw[11];   // 172 orientation parity words (bit i = par(i&T))
    unsigned pad[2];     // 216 -> 224 B (14 uint4)
};
struct ParamsG {
    PassG pass[MAXP];
    unsigned ms[NQ];      // final Z_w selector masks (address space)
    unsigned fmask[NQ];   // bit i = par(cmb_last[i] & ms[w])
    unsigned initIW[10];  // bit w = physical-bit_w contribution of R0[j]
};

struct C2x2 { float2 m[2][2]; };

__device__ __forceinline__ float2 cmul(float2 a, float2 b) {
    return make_float2(a.x * b.x - a.y * b.y, a.x * b.y + a.y * b.x);
}
__device__ __forceinline__ float2 cmac(float2 acc, float2 a, float2 b) {
    acc.x = fmaf(a.x, b.x, fmaf(-a.y, b.y, acc.x));
    acc.y = fmaf(a.x, b.y, fmaf(a.y, b.x, acc.y));
    return acc;
}

// PennyLane Rot(phi,theta,omega) = RZ(omega) RY(theta) RZ(phi)
__device__ __forceinline__ C2x2 rot_gate(const float* qp) {
    float phi = qp[0], th = qp[1], om = qp[2];
    float ct, stt; __sincosf(0.5f * th, &stt, &ct);
    float sa, ca; __sincosf(0.5f * (phi + om), &sa, &ca);
    float sb, cb; __sincosf(0.5f * (phi - om), &sb, &cb);
    C2x2 G;
    G.m[0][0] = make_float2(ca * ct, -sa * ct);
    G.m[0][1] = make_float2(-cb * stt, -sb * stt);
    G.m[1][0] = make_float2(cb * stt, -sb * stt);
    G.m[1][1] = make_float2(ca * ct, sa * ct);
    return G;
}

// G := G * RX(ang)   (RX applied first to the state)
__device__ __forceinline__ C2x2 fuse_rx(C2x2 G, float ang) {
    float sh, ch; __sincosf(0.5f * ang, &sh, &ch);
    float2 c = make_float2(ch, 0.f), is = make_float2(0.f, -sh);
    C2x2 R;
    #pragma unroll
    for (int i = 0; i < 2; ++i) {
        R.m[i][0] = cmac(cmul(G.m[i][0], c), G.m[i][1], is);
        R.m[i][1] = cmac(cmul(G.m[i][1], c), G.m[i][0], is);
    }
    return R;
}

// load one pass's header params into registers (global loads -> vmcnt domain)
__device__ __forceinline__ void load_pass(const PassG* __restrict__ p, int tid,
        unsigned cmb[16], unsigned gidx[4], unsigned& nw, unsigned& r)
{
    const uint4* c4 = (const uint4*)p->cmb8;
    uint4 u0 = c4[0], u1 = c4[1], u2 = c4[2], u3 = c4[3];
    cmb[0] = u0.x; cmb[1] = u0.y; cmb[2]  = u0.z; cmb[3]  = u0.w;
    cmb[4] = u1.x; cmb[5] = u1.y; cmb[6]  = u1.z; cmb[7]  = u1.w;
    cmb[8] = u2.x; cmb[9] = u2.y; cmb[10] = u2.z; cmb[11] = u2.w;
    cmb[12] = u3.x; cmb[13] = u3.y; cmb[14] = u3.z; cmb[15] = u3.w;
    unsigned rr = 0;
    #pragma unroll
    for (int j = 0; j < 10; ++j)
        rr ^= ((tid >> j) & 1) ? p->R[j] : 0u;
    r = rr;
    #pragma unroll
    for (int q = 0; q < 4; ++q) gidx[q] = p->gidx[q];
    nw = p->nw;
}

// apply one span-member ("extra") gate: pairs (i, i^C); per-pair orientation
// bit = par(s_g & rep) ^ par(s_g & cmb_i) = og ^ parw[i]; all register
// indices compile-time (rule #20).
template<int C>
__device__ __forceinline__ void apply_extra(float2 a[16], const float2* gb,
        unsigned w1, unsigned pw, unsigned rep)
{
    const unsigned sga = w1 & 0x3FFFu;
    const int gi = (int)(w1 >> 16) * 4;
    const unsigned og = __popc(rep & sga) & 1u;
    const unsigned swv = pw ^ (og ? 0xFFFFu : 0u);
    float2 g00 = gb[gi + 0], g01 = gb[gi + 1], g10 = gb[gi + 2], g11 = gb[gi + 3];
    const int LB = C & (-C);
    #pragma unroll
    for (int i = 0; i < 16; ++i) {
        if (!(i & LB)) {
            const int i1 = i ^ C;
            const bool sw = (swv >> i) & 1u;
            float2 x0 = sw ? a[i1] : a[i];
            float2 x1 = sw ? a[i]  : a[i1];
            float2 n0 = cmac(cmul(g00, x0), g01, x1);
            float2 n1 = cmac(cmul(g10, x0), g11, x1);
            a[i]  = sw ? n1 : n0;
            a[i1] = sw ? n0 : n1;
        }
    }
}

// basis gates: unit combos, orientation = logical bit q (host-normalized reps)
#define APPLY_BASIS()                                                       \
    {                                                                       \
        _Pragma("unroll")                                                   \
        for (int q = 0; q < 4; ++q) {                                       \
            if (q < (int)nwr) {    /* wave-uniform branch */                \
                const int gi = (int)gidxr[q] * 4;                           \
                float2 g00 = gbuf[gi + 0], g01 = gbuf[gi + 1];              \
                float2 g10 = gbuf[gi + 2], g11 = gbuf[gi + 3];              \
                _Pragma("unroll")                                           \
                for (int i = 0; i < 16; ++i) {                              \
                    if (!((i >> q) & 1)) {                                  \
                        const int i1 = i | (1 << q);                        \
                        float2 a0 = a[i], a1 = a[i1];                       \
                        float2 n0 = cmac(cmul(g00, a0), g01, a1);           \
                        float2 n1 = cmac(cmul(g10, a0), g11, a1);           \
                        a[i] = n0; a[i1] = n1;                              \
                    }                                                       \
                }                                                           \
            }                                                               \
        }                                                                   \
    }

// extras block: 6 uint4 at byte offset 128 of PassG; slot k: w1=eg[k], pw=parw[k]
#define APPLY_EXTRAS()                                                      \
    {                                                                       \
        if (epm) {                                                          \
            if (epm & (1u<<0))  apply_extra<3> (a, gbuf, E0.x, E2.w, rn);   \
            if (epm & (1u<<1))  apply_extra<5> (a, gbuf, E0.y, E3.x, rn);   \
            if (epm & (1u<<2))  apply_extra<6> (a, gbuf, E0.z, E3.y, rn);   \
            if (epm & (1u<<3))  apply_extra<9> (a, gbuf, E0.w, E3.z, rn);   \
            if (epm & (1u<<4))  apply_extra<10>(a, gbuf, E1.x, E3.w, rn);   \
            if (epm & (1u<<5))  apply_extra<12>(a, gbuf, E1.y, E4.x, rn);   \
            if (epm & (1u<<6))  apply_extra<7> (a, gbuf, E1.z, E4.y, rn);   \
            if (epm & (1u<<7))  apply_extra<11>(a, gbuf, E1.w, E4.z, rn);   \
            if (epm & (1u<<8))  apply_extra<13>(a, gbuf, E2.x, E4.w, rn);   \
            if (epm & (1u<<9))  apply_extra<14>(a, gbuf, E2.y, E5.x, rn);   \
            if (epm & (1u<<10)) apply_extra<15>(a, gbuf, E2.z, E5.y, rn);   \
        }                                                                   \
    }

__global__ __launch_bounds__(BT) void qsim_kernel(
    const float* __restrict__ x, const float* __restrict__ qw,
    const float* __restrict__ wl, const float* __restrict__ bl,
    float* __restrict__ out, const ParamsG* __restrict__ pp, int np)
{
    __shared__ float2 st[NSTATE];          // 128 KB state
    __shared__ float2 gbuf[NL * NQ * 4];   // 42 precomputed 2x2 gates
    __shared__ float2 ubuf[NQ][2];         // per-wire layer-0 2-vectors u_w
    __shared__ float red[NWAVES];

    const int tid = threadIdx.x;
    const int b = blockIdx.x;

    // precompute all 2x2 gates once (layer 0 fuses the RX embedding);
    // layer-0 gates additionally publish u_w = G*(1,0)^T for the init
    if (tid < NL * NQ) {
        int l = tid / NQ, w = tid % NQ;
        C2x2 G = rot_gate(qw + tid * 3);
        if (l == 0) {
            G = fuse_rx(G, x[b * NQ + w]);
            ubuf[w][0] = G.m[0][0];
            ubuf[w][1] = G.m[1][0];
        }
        gbuf[tid * 4 + 0] = G.m[0][0];
        gbuf[tid * 4 + 1] = G.m[0][1];
        gbuf[tid * 4 + 2] = G.m[1][0];
        gbuf[tid * 4 + 3] = G.m[1][1];
    }

    char* sb = (char*)st;
    float2 a[16];
    unsigned addr[16];
    unsigned cmbreg[16], gidxr[4], nwr, rn;

    load_pass(&pp->pass[0], tid, cmbreg, gidxr, nwr, rn);

    // physical bits (wires 0..9) of this thread's init rep: GF(2)-linear in tid
    unsigned b0 = 0;
    #pragma unroll
    for (int j = 0; j < 10; ++j)
        b0 ^= ((tid >> j) & 1) ? pp->initIW[j] : 0u;

    __syncthreads();   // gbuf + ubuf ready

    // ---- pass 0: analytic product-state init (layer 0 never entangles) ----
    // amp(rep ^ cmb_i) = [prod_{w=0..9} u_w[bit_w(rep)]] * prod_q u_{10+q}[i_q]
    {
        const unsigned rb = rn << 3;
        float2 c = ubuf[0][b0 & 1];
        #pragma unroll
        for (int w = 1; w < 10; ++w)
            c = cmul(c, ubuf[w][(b0 >> w) & 1]);
        a[0] = cmul(c, ubuf[10][0]);
        a[1] = cmul(c, ubuf[10][1]);
        #pragma unroll
        for (int i = 0; i < 2; ++i) {
            a[2 + i] = cmul(a[i], ubuf[11][1]);
            a[i]     = cmul(a[i], ubuf[11][0]);
        }
        #pragma unroll
        for (int i = 0; i < 4; ++i) {
            a[4 + i] = cmul(a[i], ubuf[12][1]);
            a[i]     = cmul(a[i], ubuf[12][0]);
        }
        #pragma unroll
        for (int i = 0; i < 8; ++i) {
            a[8 + i] = cmul(a[i], ubuf[13][1]);
            a[i]     = cmul(a[i], ubuf[13][0]);
        }
        #pragma unroll
        for (int i = 0; i < 16; ++i)
            *(float2*)(sb + (rb ^ cmbreg[i])) = a[i];   // this IS the state init
    }

    load_pass(&pp->pass[1], tid, cmbreg, gidxr, nwr, rn);

    #pragma unroll 1
    for (int ps = 1; ps < np - 1; ++ps) {
        __syncthreads();   // previous pass's writes visible
        const unsigned rb = rn << 3;
        #pragma unroll
        for (int i = 0; i < 16; ++i) addr[i] = rb ^ cmbreg[i];
        // extras block of the CURRENT pass (vmcnt; consumed after basis)
        const uint4* Eb = (const uint4*)((const char*)&pp->pass[ps] + 128);
        uint4 E0 = Eb[0], E1 = Eb[1], E2 = Eb[2], E3 = Eb[3], E4 = Eb[4], E5 = Eb[5];
        const unsigned epm = pp->pass[ps].epm;
        #pragma unroll
        for (int i = 0; i < 16; ++i)
            a[i] = *(const float2*)(sb + addr[i]);
        // prefetch next pass's header during this pass's compute
        unsigned cmbn[16], gidxn[4], nwn, rnn;
        load_pass(&pp->pass[ps + 1], tid, cmbn, gidxn, nwn, rnn);
        APPLY_BASIS();
        APPLY_EXTRAS();
        #pragma unroll
        for (int i = 0; i < 16; ++i)
            *(float2*)(sb + addr[i]) = a[i];
        #pragma unroll
        for (int i = 0; i < 16; ++i) cmbreg[i] = cmbn[i];
        #pragma unroll
        for (int q = 0; q < 4; ++q) gidxr[q] = gidxn[q];
        nwr = nwn; rn = rnn;
    }

    // ---- final pass: reads + gates, measurement straight from registers ----
    float acc = 0.f;
    {
        const int ps = np - 1;
        __syncthreads();
        const unsigned rb = rn << 3;
        #pragma unroll
        for (int i = 0; i < 16; ++i) addr[i] = rb ^ cmbreg[i];
        const uint4* Eb = (const uint4*)((const char*)&pp->pass[ps] + 128);
        uint4 E0 = Eb[0], E1 = Eb[1], E2 = Eb[2], E3 = Eb[3], E4 = Eb[4], E5 = Eb[5];
        const unsigned epm = pp->pass[ps].epm;
        #pragma unroll
        for (int i = 0; i < 16; ++i)
            a[i] = *(const float2*)(sb + addr[i]);
        APPLY_BASIS();
        APPLY_EXTRAS();

        // weight of amp at address rn^cmb_i: sign_w = par(rn&ms_w) ^ fmask_w[i]
        float A[16];
        #pragma unroll
        for (int i = 0; i < 16; ++i) A[i] = 0.f;
        #pragma unroll
        for (int w = 0; w < NQ; ++w) {
            float v = wl[w];
            unsigned p0 = __popc(rn & pp->ms[w]) & 1u;
            float vs = p0 ? -v : v;
            const unsigned fm = pp->fmask[w];
            #pragma unroll
            for (int i = 0; i < 16; ++i)
                A[i] += ((fm >> i) & 1u) ? -vs : vs;
        }
        #pragma unroll
        for (int i = 0; i < 16; ++i)
            acc = fmaf(fmaf(a[i].x, a[i].x, a[i].y * a[i].y), A[i], acc);
    }

    #pragma unroll
    for (int off = 32; off > 0; off >>= 1) acc += __shfl_down(acc, off, 64);
    if ((tid & 63) == 0) red[tid >> 6] = acc;
    __syncthreads();
    if (tid == 0) {
        float s2 = 0.f;
        #pragma unroll
        for (int i = 0; i < NWAVES; ++i) s2 += red[i];
        out[b] = s2 + bl[0];
    }
}

// ---- host-side GF(2) helpers ----
struct GF2Basis {
    unsigned piv[NQ];
    GF2Basis() { for (int i = 0; i < NQ; ++i) piv[i] = 0; }
    bool insert(unsigned v) {            // true iff rank increased
        for (int bb = NQ - 1; bb >= 0; --bb) {
            if (!((v >> bb) & 1)) continue;
            if (piv[bb]) v ^= piv[bb];
            else { piv[bb] = v; return true; }
        }
        return false;
    }
};

static inline int par16(unsigned v) { return __builtin_parity(v); }
static inline unsigned lcg_next(unsigned& s) { s = s * 1664525u + 1013904223u; return s >> 8; }

static unsigned gf_apply(const unsigned* C, unsigned v) {
    unsigned r = 0;
    while (v) { int j = __builtin_ctz(v); v &= v - 1; r ^= C[j]; }
    return r;
}

// C = columns of sigma; on success Ci = columns of sigma^{-1}
static bool gf_invert(const unsigned* C, unsigned* Ci) {
    unsigned rows[NQ], irows[NQ];
    for (int i = 0; i < NQ; ++i) {
        unsigned r = 0;
        for (int j = 0; j < NQ; ++j) r |= ((C[j] >> i) & 1u) << j;
        rows[i] = r; irows[i] = 1u << i;
    }
    for (int c = 0; c < NQ; ++c) {
        int p = -1;
        for (int r = c; r < NQ; ++r) if ((rows[r] >> c) & 1u) { p = r; break; }
        if (p < 0) return false;
        unsigned t = rows[p]; rows[p] = rows[c]; rows[c] = t;
        t = irows[p]; irows[p] = irows[c]; irows[c] = t;
        for (int r = 0; r < NQ; ++r)
            if (r != c && ((rows[r] >> c) & 1u)) { rows[r] ^= rows[c]; irows[r] ^= irows[c]; }
    }
    for (int j = 0; j < NQ; ++j) {
        unsigned col = 0;
        for (int i = 0; i < NQ; ++i) col |= ((irows[i] >> j) & 1u) << i;
        Ci[j] = col;
    }
    return true;
}

extern "C" void kernel_launch(void* const* d_in, const int* in_sizes, int n_in,
                              void* d_out, int out_size, void* d_ws, size_t ws_size,
                              hipStream_t stream) {
    const float* x  = (const float*)d_in[0];   // (B, 14)
    const float* qw = (const float*)d_in[1];   // (3, 14, 3)
    const float* wl = (const float*)d_in[2];   // (1, 14)
    const float* bl = (const float*)d_in[3];   // (1,)
    float* out = (float*)d_out;                // (B, 1)

    const int B = in_sizes[0] / NQ;

    // slot menu: combo value per extra slot (must match device APPLY_EXTRAS)
    static const int EXC[NEX] = {3, 5, 6, 9, 10, 12, 7, 11, 13, 14, 15};
    int c2s[16]; for (int i = 0; i < 16; ++i) c2s[i] = -1;
    for (int k = 0; k < NEX; ++k) c2s[EXC[k]] = k;

    // ---- build gate list (LAYERS 1-2 ONLY; layer 0 = analytic init) in
    // circuit order with (s,m) captured per gate. Rings (incl. layer 0's)
    // are folded into the frame in circuit order.
    unsigned gs[NL * NQ], gm[NL * NQ];
    int ggi[NL * NQ];
    unsigned s[NQ], m[NQ], msIdx[NQ];
    for (int w = 0; w < NQ; ++w) s[w] = m[w] = 1u << (NQ - 1 - w); // wire 0 = MSB
    int ng = 0;
    for (int l = 0; l < NL; ++l) {
        if (l > 0) {
            for (int w = 0; w < NQ; ++w) {
                gs[ng] = s[w]; gm[ng] = m[w]; ggi[ng] = l * NQ + w; ++ng;
            }
        }
        int r = (l % (NQ - 1)) + 1;            // PennyLane ranges: 1,2,3
        for (int w = 0; w < NQ; ++w) {         // CNOT ring: control w, target (w+r)%NQ
            int c = w, t = (w + r) % NQ;
            s[t] ^= s[c];
            m[c] ^= m[t];
        }
    }
    for (int w = 0; w < NQ; ++w) msIdx[w] = s[w];

    struct Raw {
        unsigned rv[10], cmb[16];
        unsigned char gidx[4], nw;
        int exgate[NEX];          // gbuf index or -1
        unsigned exsel[NEX];      // selector (index space)
        unsigned exT[NEX];        // 4-bit basis-parity vector
    } raw[MAXP];
    for (int p = 0; p < MAXP; ++p)
        for (int k = 0; k < NEX; ++k) raw[p].exgate[k] = -1;

    // ---- entry 0: init group aligned to wires 10..13 (index space units) ----
    {
        unsigned mm[4];
        for (int q = 0; q < 4; ++q) mm[q] = 1u << (3 - q);    // wire 10+q
        for (int j = 0; j < 10; ++j) raw[0].rv[j] = 1u << (13 - j); // wires 0..9
        for (int idx = 0; idx < 16; ++idx) {
            unsigned c = 0;
            for (int q = 0; q < 4; ++q) if ((idx >> q) & 1) c ^= mm[q];
            raw[0].cmb[idx] = c;
        }
        for (int q = 0; q < 4; ++q) raw[0].gidx[q] = 0;
        raw[0].nw = 0;
    }

    // ---- greedy pack the 28 gates into passes (cross-layer mixing) ----
    // Basis gates (unit combos): biorthogonal + commute-with-skipped +
    // independent masks. Extras (span-member combos): applied AFTER the
    // basis in the same LDS round trip; accepted iff they commute with
    // already-accepted extras, with later-in-circuit in-pass basis gates,
    // and with all earlier-in-circuit unapplied gates.
    bool used[NL * NQ] = {false};
    int np = 1, remaining = ng;
    while (remaining > 0 && np < MAXP) {
        unsigned pss[4], pmm[4];
        int pgi[4], nw = 0;
        GF2Basis gf;
        for (int g = 0; g < ng && nw < 4; ++g) {
            if (used[g]) continue;
            bool ok = true;
            for (int k = 0; k < nw && ok; ++k)
                if (par16(gs[g] & pmm[k]) || par16(pss[k] & gm[g])) ok = false;
            for (int h = 0; h < g && ok; ++h)
                if (!used[h] && (par16(gs[g] & gm[h]) || par16(gs[h] & gm[g]))) ok = false;
            if (!ok) continue;
            GF2Basis trial = gf;
            if (!trial.insert(gm[g])) continue;
            gf = trial;
            pss[nw] = gs[g]; pmm[nw] = gm[g]; pgi[nw] = g; ++nw;
            used[g] = true; --remaining;
        }
        // pad to 4 independent masks; normalize pads so they don't flip the
        // real wires' logical bits
        unsigned mm[4], ss[4];
        for (int i = 0; i < nw; ++i) { mm[i] = pmm[i]; ss[i] = pss[i]; }
        for (int i = nw; i < 4; ++i) {
            unsigned cand = 0;
            for (int t = 0; t < NQ; ++t)
                if (gf.insert(1u << t)) { cand = 1u << t; break; }
            for (int j = 0; j < nw; ++j)
                if (par16(cand & ss[j])) cand ^= mm[j];
            mm[i] = cand; ss[i] = 0;
        }
        // complement basis (10 vecs), normalized to zero logical bits
        int nR = 0;
        for (int t = 0; t < NQ && nR < 10; ++t) {
            if (gf.insert(1u << t)) {
                unsigned v = 1u << t;
                for (int j = 0; j < nw; ++j)
                    if (par16(v & ss[j])) v ^= mm[j];
                raw[np].rv[nR++] = v;
            }
        }
        for (int idx = 0; idx < 16; ++idx) {
            unsigned c = 0;
            for (int q = 0; q < 4; ++q) if ((idx >> q) & 1) c ^= mm[q];
            raw[np].cmb[idx] = c;
        }
        for (int q = 0; q < 4; ++q)
            raw[np].gidx[q] = (unsigned char)(q < nw ? ggi[pgi[q]] : 0);
        raw[np].nw = (unsigned char)nw;

        // ---- extras sweep: span-member gates in circuit order ----
        {
            int exCirc[NEX]; int nExtra = 0;
            for (int g = 0; g < ng; ++g) {
                if (used[g]) continue;
                int c = -1;
                for (int t2 = 3; t2 < 16; ++t2) {
                    if (__builtin_popcount((unsigned)t2) < 2) continue;
                    unsigned xr = 0;
                    for (int j = 0; j < 4; ++j) if ((t2 >> j) & 1) xr ^= mm[j];
                    if (xr == gm[g]) { c = t2; break; }
                }
                if (c < 0) continue;
                int slot = c2s[c];
                if (slot < 0 || raw[np].exgate[slot] >= 0) continue;
                // T = basis-parity vector; parity of T over combo bits must
                // be 1 (duality invariant; checked as a sanity filter)
                unsigned T = 0;
                for (int j = 0; j < 4; ++j)
                    T |= (unsigned)(par16(mm[j] & gs[g]) & 1) << j;
                {
                    int sp = 0;
                    for (int j = 0; j < 4; ++j) if ((c >> j) & 1) sp ^= (T >> j) & 1;
                    if (!sp) continue;
                }
                bool ok = true;
                for (int e = 0; e < nExtra && ok; ++e) {
                    int h = exCirc[e];
                    if (par16(gs[g] & gm[h]) || par16(gs[h] & gm[g])) ok = false;
                }
                for (int kk = 0; kk < nw && ok; ++kk) {
                    int h = pgi[kk];
                    if (h > g && (par16(gs[g] & gm[h]) || par16(gs[h] & gm[g]))) ok = false;
                }
                for (int h = 0; h < g && ok; ++h)
                    if (!used[h] && (par16(gs[g] & gm[h]) || par16(gs[h] & gm[g]))) ok = false;
                if (!ok) continue;
                raw[np].exgate[slot] = ggi[g];
                raw[np].exsel[slot] = gs[g];
                raw[np].exT[slot] = T;
                exCirc[nExtra++] = g;
                used[g] = true; --remaining;
            }
        }
        ++np;
    }

    // ---- choose layout sigma: every entry's rep space (incl. init) must
    // project with full rank 4 onto the bank-pair bits (addr mod 16) ----
    unsigned Cm[NQ], Ci[NQ];
    unsigned seed = 0x9E3779B9u;
    bool found = false;
    for (int tries = 0; tries < 5000 && !found; ++tries) {
        for (int j = 0; j < NQ; ++j) Cm[j] = lcg_next(seed) & (NSTATE - 1);
        if (!gf_invert(Cm, Ci)) continue;
        found = true;
        for (int p = 0; p < np && found; ++p) {
            unsigned piv[4] = {0, 0, 0, 0}; int npv = 0;
            for (int i = 0; i < 10; ++i) {
                unsigned w2 = gf_apply(Cm, raw[p].rv[i]);
                for (int bb = 0; bb < 4; ++bb)
                    if (((w2 >> bb) & 1u) && piv[bb]) w2 ^= piv[bb];
                if ((w2 & 15u) && npv < 4) { piv[__builtin_ctz(w2 & 15u)] = w2; ++npv; }
            }
            if (npv < 4) found = false;
        }
    }
    if (!found) {  // fallback: identity layout (correct, just slower)
        for (int j = 0; j < NQ; ++j) Cm[j] = 1u << j;
        gf_invert(Cm, Ci);
    }

    // ---- emit device params in ADDRESS space into the global table ----
    static ParamsG h_pg;                // static: stable across graph replays
    memset(&h_pg, 0, sizeof(h_pg));
    for (int p = 0; p < np; ++p) {
        unsigned u[10];
        for (int i = 0; i < 10; ++i) u[i] = gf_apply(Cm, raw[p].rv[i]);
        // order: 4 bank-pivot vectors first (they cover lane bits 0..3)
        unsigned piv[4] = {0, 0, 0, 0};
        int ord[10], npv = 0, rest[10], nrest = 0;
        for (int i = 0; i < 10; ++i) {
            unsigned w2 = u[i];
            for (int bb = 0; bb < 4; ++bb)
                if (((w2 >> bb) & 1u) && piv[bb]) w2 ^= piv[bb];
            if ((w2 & 15u) && npv < 4) { piv[__builtin_ctz(w2 & 15u)] = w2; ord[npv++] = i; }
            else rest[nrest++] = i;
        }
        int kk = 0;
        for (int i = 0; i < npv; ++i) h_pg.pass[p].R[kk++] = u[ord[i]];
        for (int i = 0; i < nrest; ++i) h_pg.pass[p].R[kk++] = u[rest[i]];
        for (int idx = 0; idx < 16; ++idx)
            h_pg.pass[p].cmb8[idx] = gf_apply(Cm, raw[p].cmb[idx]) << 3;
        for (int q = 0; q < 4; ++q) h_pg.pass[p].gidx[q] = raw[p].gidx[q];
        h_pg.pass[p].nw = raw[p].nw;
        // extras: sga = sigma^{-T}(s_g); parw[i] = popc(i & T) & 1
        unsigned epm = 0;
        for (int k = 0; k < NEX; ++k) {
            if (raw[p].exgate[k] < 0) continue;
            epm |= 1u << k;
            unsigned sga = 0;
            for (int i = 0; i < NQ; ++i)
                sga |= (unsigned)(par16(Ci[i] & raw[p].exsel[k]) & 1) << i;
            h_pg.pass[p].eg[k] = sga | ((unsigned)raw[p].exgate[k] << 16);
            unsigned T = raw[p].exT[k], pw = 0;
            for (int i = 0; i < 16; ++i)
                pw |= (unsigned)(__builtin_popcount(i & T) & 1) << i;
            h_pg.pass[p].parw[k] = pw;
        }
        h_pg.pass[p].epm = epm;
    }
    // measurement masks: par(sigma^{-1}(t) & ms) = par(t & sigma^{-T} ms)
    for (int w = 0; w < NQ; ++w) {
        unsigned msp = 0;
        for (int i = 0; i < NQ; ++i)
            msp |= (unsigned)(par16(Ci[i] & msIdx[w]) & 1) << i;
        h_pg.ms[w] = msp;
    }
    // combo-part parities of the FINAL pass (measurement runs from registers;
    // cmb8 is pre-shifted, ms is in address space -> compare unshifted)
    for (int w = 0; w < NQ; ++w) {
        unsigned fm = 0;
        for (int i = 0; i < 16; ++i)
            fm |= (unsigned)(par16((h_pg.pass[np - 1].cmb8[i] >> 3) & h_pg.ms[w]) & 1) << i;
        h_pg.fmask[w] = fm;
    }
    // init physical-bit tables: bit_w(sigma^{-1}(a)) = par(a & t_w), with
    // t_w = sigma^{-T}(unit of wire w); IW[j] packs par(R0[j] & t_w) at bit w.
    {
        unsigned tmask[NQ];
        for (int w = 0; w < NQ; ++w) {
            unsigned t = 0;
            for (int i = 0; i < NQ; ++i)
                t |= (unsigned)((Ci[i] >> (NQ - 1 - w)) & 1u) << i;
            tmask[w] = t;
        }
        for (int j = 0; j < 10; ++j) {
            unsigned iw = 0;
            for (int w = 0; w < NQ; ++w)
                iw |= (unsigned)(par16(h_pg.pass[0].R[j] & tmask[w]) & 1) << w;
            h_pg.initIW[j] = iw;
        }
    }

    ParamsG* d_pg = (ParamsG*)d_ws;
    hipMemcpyAsync(d_pg, &h_pg, sizeof(ParamsG), hipMemcpyHostToDevice, stream);
    qsim_kernel<<<dim3(B), dim3(BT), 0, stream>>>(x, qw, wl, bl, out, d_pg, np);
}

// Round 7
// 102.602 us; speedup vs baseline: 1.0014x; 1.0014x over previous
//
#include <hip/hip_runtime.h>
#include <string.h>

#define NQ 14
#define NSTATE (1 << NQ)       // 16384 amplitudes
#define NL 3
#define MAXP 12                // max table entries (init + gate passes)
#define BT 1024                // threads per block
#define NWAVES (BT / 64)
#define NEX 11                 // extra-gate combo menu size

// Lazily-permuted simulation: CNOT rings folded into GF(2) index maps, and a
// global GF(2)-linear LDS layout sigma (amp p stored at address sigma(p)).
// sigma is chosen host-side so that EVERY pass's representative space
// projects with full rank 4 onto the bank-pair bits (addr mod 16).
// Verified structure (round 5): analytic product-state init for layer 0,
// fused measurement, vmcnt-domain param prefetch, scalar float2 complex
// math, span-closure extras (8 gates absorbed -> 5 gate passes).
// This round's single change: __launch_bounds__(BT, 4). With LDS already
// capping us at 1 block/CU (16 waves, 4/SIMD), the legal VGPR budget is
// 128 — but without the second arg hipcc budgeted for 2 blocks/CU (64
// VGPR) and rematerialized addresses / re-loaded the extras table from
// global per use (FETCH 167->234 KB, mid-pass vmcnt stalls). Declaring
// min-4-waves/EU unlocks the full 128-VGPR file at zero occupancy cost.
struct PassG {
    unsigned cmb8[16];   // 0   XOR combos of pair masks, pre-shifted <<3
    unsigned R[10];      // 64  complement-basis images (tid -> rep)
    unsigned gidx[4];    // 104 basis gate table indices
    unsigned nw;         // 120 real basis gates in this pass
    unsigned epm;        // 124 extra-present mask (bit k = slot k active)
    unsigned eg[11];     // 128 sga(14b) | gidx<<16
    unsigned parw[11];   // 172 orientation parity words (bit i = par(i&T))
    unsigned pad[2];     // 216 -> 224 B (14 uint4)
};
struct ParamsG {
    PassG pass[MAXP];
    unsigned ms[NQ];      // final Z_w selector masks (address space)
    unsigned fmask[NQ];   // bit i = par(cmb_last[i] & ms[w])
    unsigned initIW[10];  // bit w = physical-bit_w contribution of R0[j]
};

struct C2x2 { float2 m[2][2]; };

__device__ __forceinline__ float2 cmul(float2 a, float2 b) {
    return make_float2(a.x * b.x - a.y * b.y, a.x * b.y + a.y * b.x);
}
__device__ __forceinline__ float2 cmac(float2 acc, float2 a, float2 b) {
    acc.x = fmaf(a.x, b.x, fmaf(-a.y, b.y, acc.x));
    acc.y = fmaf(a.x, b.y, fmaf(a.y, b.x, acc.y));
    return acc;
}

// PennyLane Rot(phi,theta,omega) = RZ(omega) RY(theta) RZ(phi)
__device__ __forceinline__ C2x2 rot_gate(const float* qp) {
    float phi = qp[0], th = qp[1], om = qp[2];
    float ct, stt; __sincosf(0.5f * th, &stt, &ct);
    float sa, ca; __sincosf(0.5f * (phi + om), &sa, &ca);
    float sb, cb; __sincosf(0.5f * (phi - om), &sb, &cb);
    C2x2 G;
    G.m[0][0] = make_float2(ca * ct, -sa * ct);
    G.m[0][1] = make_float2(-cb * stt, -sb * stt);
    G.m[1][0] = make_float2(cb * stt, -sb * stt);
    G.m[1][1] = make_float2(ca * ct, sa * ct);
    return G;
}

// G := G * RX(ang)   (RX applied first to the state)
__device__ __forceinline__ C2x2 fuse_rx(C2x2 G, float ang) {
    float sh, ch; __sincosf(0.5f * ang, &sh, &ch);
    float2 c = make_float2(ch, 0.f), is = make_float2(0.f, -sh);
    C2x2 R;
    #pragma unroll
    for (int i = 0; i < 2; ++i) {
        R.m[i][0] = cmac(cmul(G.m[i][0], c), G.m[i][1], is);
        R.m[i][1] = cmac(cmul(G.m[i][1], c), G.m[i][0], is);
    }
    return R;
}

// load one pass's header params into registers (global loads -> vmcnt domain)
__device__ __forceinline__ void load_pass(const PassG* __restrict__ p, int tid,
        unsigned cmb[16], unsigned gidx[4], unsigned& nw, unsigned& r)
{
    const uint4* c4 = (const uint4*)p->cmb8;
    uint4 u0 = c4[0], u1 = c4[1], u2 = c4[2], u3 = c4[3];
    cmb[0] = u0.x; cmb[1] = u0.y; cmb[2]  = u0.z; cmb[3]  = u0.w;
    cmb[4] = u1.x; cmb[5] = u1.y; cmb[6]  = u1.z; cmb[7]  = u1.w;
    cmb[8] = u2.x; cmb[9] = u2.y; cmb[10] = u2.z; cmb[11] = u2.w;
    cmb[12] = u3.x; cmb[13] = u3.y; cmb[14] = u3.z; cmb[15] = u3.w;
    unsigned rr = 0;
    #pragma unroll
    for (int j = 0; j < 10; ++j)
        rr ^= ((tid >> j) & 1) ? p->R[j] : 0u;
    r = rr;
    #pragma unroll
    for (int q = 0; q < 4; ++q) gidx[q] = p->gidx[q];
    nw = p->nw;
}

// apply one span-member ("extra") gate: pairs (i, i^C); per-pair orientation
// bit = par(s_g & rep) ^ par(s_g & cmb_i) = og ^ parw[i]; all register
// indices compile-time (rule #20).
template<int C>
__device__ __forceinline__ void apply_extra(float2 a[16], const float2* gb,
        unsigned w1, unsigned pw, unsigned rep)
{
    const unsigned sga = w1 & 0x3FFFu;
    const int gi = (int)(w1 >> 16) * 4;
    const unsigned og = __popc(rep & sga) & 1u;
    const unsigned swv = pw ^ (og ? 0xFFFFu : 0u);
    float2 g00 = gb[gi + 0], g01 = gb[gi + 1], g10 = gb[gi + 2], g11 = gb[gi + 3];
    const int LB = C & (-C);
    #pragma unroll
    for (int i = 0; i < 16; ++i) {
        if (!(i & LB)) {
            const int i1 = i ^ C;
            const bool sw = (swv >> i) & 1u;
            float2 x0 = sw ? a[i1] : a[i];
            float2 x1 = sw ? a[i]  : a[i1];
            float2 n0 = cmac(cmul(g00, x0), g01, x1);
            float2 n1 = cmac(cmul(g10, x0), g11, x1);
            a[i]  = sw ? n1 : n0;
            a[i1] = sw ? n0 : n1;
        }
    }
}

// basis gates: unit combos, orientation = logical bit q (host-normalized reps)
#define APPLY_BASIS()                                                       \
    {                                                                       \
        _Pragma("unroll")                                                   \
        for (int q = 0; q < 4; ++q) {                                       \
            if (q < (int)nwr) {    /* wave-uniform branch */                \
                const int gi = (int)gidxr[q] * 4;                           \
                float2 g00 = gbuf[gi + 0], g01 = gbuf[gi + 1];              \
                float2 g10 = gbuf[gi + 2], g11 = gbuf[gi + 3];              \
                _Pragma("unroll")                                           \
                for (int i = 0; i < 16; ++i) {                              \
                    if (!((i >> q) & 1)) {                                  \
                        const int i1 = i | (1 << q);                        \
                        float2 a0 = a[i], a1 = a[i1];                       \
                        float2 n0 = cmac(cmul(g00, a0), g01, a1);           \
                        float2 n1 = cmac(cmul(g10, a0), g11, a1);           \
                        a[i] = n0; a[i1] = n1;                              \
                    }                                                       \
                }                                                           \
            }                                                               \
        }                                                                   \
    }

// extras block: 6 uint4 at byte offset 128 of PassG; slot k: w1=eg[k], pw=parw[k]
#define APPLY_EXTRAS()                                                      \
    {                                                                       \
        if (epm) {                                                          \
            if (epm & (1u<<0))  apply_extra<3> (a, gbuf, E0.x, E2.w, rn);   \
            if (epm & (1u<<1))  apply_extra<5> (a, gbuf, E0.y, E3.x, rn);   \
            if (epm & (1u<<2))  apply_extra<6> (a, gbuf, E0.z, E3.y, rn);   \
            if (epm & (1u<<3))  apply_extra<9> (a, gbuf, E0.w, E3.z, rn);   \
            if (epm & (1u<<4))  apply_extra<10>(a, gbuf, E1.x, E3.w, rn);   \
            if (epm & (1u<<5))  apply_extra<12>(a, gbuf, E1.y, E4.x, rn);   \
            if (epm & (1u<<6))  apply_extra<7> (a, gbuf, E1.z, E4.y, rn);   \
            if (epm & (1u<<7))  apply_extra<11>(a, gbuf, E1.w, E4.z, rn);   \
            if (epm & (1u<<8))  apply_extra<13>(a, gbuf, E2.x, E4.w, rn);   \
            if (epm & (1u<<9))  apply_extra<14>(a, gbuf, E2.y, E5.x, rn);   \
            if (epm & (1u<<10)) apply_extra<15>(a, gbuf, E2.z, E5.y, rn);   \
        }                                                                   \
    }

__global__ __launch_bounds__(BT, 4) void qsim_kernel(
    const float* __restrict__ x, const float* __restrict__ qw,
    const float* __restrict__ wl, const float* __restrict__ bl,
    float* __restrict__ out, const ParamsG* __restrict__ pp, int np)
{
    __shared__ float2 st[NSTATE];          // 128 KB state
    __shared__ float2 gbuf[NL * NQ * 4];   // 42 precomputed 2x2 gates
    __shared__ float2 ubuf[NQ][2];         // per-wire layer-0 2-vectors u_w
    __shared__ float red[NWAVES];

    const int tid = threadIdx.x;
    const int b = blockIdx.x;

    // precompute all 2x2 gates once (layer 0 fuses the RX embedding);
    // layer-0 gates additionally publish u_w = G*(1,0)^T for the init
    if (tid < NL * NQ) {
        int l = tid / NQ, w = tid % NQ;
        C2x2 G = rot_gate(qw + tid * 3);
        if (l == 0) {
            G = fuse_rx(G, x[b * NQ + w]);
            ubuf[w][0] = G.m[0][0];
            ubuf[w][1] = G.m[1][0];
        }
        gbuf[tid * 4 + 0] = G.m[0][0];
        gbuf[tid * 4 + 1] = G.m[0][1];
        gbuf[tid * 4 + 2] = G.m[1][0];
        gbuf[tid * 4 + 3] = G.m[1][1];
    }

    char* sb = (char*)st;
    float2 a[16];
    unsigned addr[16];
    unsigned cmbreg[16], gidxr[4], nwr, rn;

    load_pass(&pp->pass[0], tid, cmbreg, gidxr, nwr, rn);

    // physical bits (wires 0..9) of this thread's init rep: GF(2)-linear in tid
    unsigned b0 = 0;
    #pragma unroll
    for (int j = 0; j < 10; ++j)
        b0 ^= ((tid >> j) & 1) ? pp->initIW[j] : 0u;

    __syncthreads();   // gbuf + ubuf ready

    // ---- pass 0: analytic product-state init (layer 0 never entangles) ----
    // amp(rep ^ cmb_i) = [prod_{w=0..9} u_w[bit_w(rep)]] * prod_q u_{10+q}[i_q]
    {
        const unsigned rb = rn << 3;
        float2 c = ubuf[0][b0 & 1];
        #pragma unroll
        for (int w = 1; w < 10; ++w)
            c = cmul(c, ubuf[w][(b0 >> w) & 1]);
        a[0] = cmul(c, ubuf[10][0]);
        a[1] = cmul(c, ubuf[10][1]);
        #pragma unroll
        for (int i = 0; i < 2; ++i) {
            a[2 + i] = cmul(a[i], ubuf[11][1]);
            a[i]     = cmul(a[i], ubuf[11][0]);
        }
        #pragma unroll
        for (int i = 0; i < 4; ++i) {
            a[4 + i] = cmul(a[i], ubuf[12][1]);
            a[i]     = cmul(a[i], ubuf[12][0]);
        }
        #pragma unroll
        for (int i = 0; i < 8; ++i) {
            a[8 + i] = cmul(a[i], ubuf[13][1]);
            a[i]     = cmul(a[i], ubuf[13][0]);
        }
        #pragma unroll
        for (int i = 0; i < 16; ++i)
            *(float2*)(sb + (rb ^ cmbreg[i])) = a[i];   // this IS the state init
    }

    load_pass(&pp->pass[1], tid, cmbreg, gidxr, nwr, rn);

    #pragma unroll 1
    for (int ps = 1; ps < np - 1; ++ps) {
        __syncthreads();   // previous pass's writes visible
        const unsigned rb = rn << 3;
        #pragma unroll
        for (int i = 0; i < 16; ++i) addr[i] = rb ^ cmbreg[i];
        // extras block of the CURRENT pass (vmcnt; consumed after basis)
        const uint4* Eb = (const uint4*)((const char*)&pp->pass[ps] + 128);
        uint4 E0 = Eb[0], E1 = Eb[1], E2 = Eb[2], E3 = Eb[3], E4 = Eb[4], E5 = Eb[5];
        const unsigned epm = pp->pass[ps].epm;
        #pragma unroll
        for (int i = 0; i < 16; ++i)
            a[i] = *(const float2*)(sb + addr[i]);
        // prefetch next pass's header during this pass's compute
        unsigned cmbn[16], gidxn[4], nwn, rnn;
        load_pass(&pp->pass[ps + 1], tid, cmbn, gidxn, nwn, rnn);
        APPLY_BASIS();
        APPLY_EXTRAS();
        #pragma unroll
        for (int i = 0; i < 16; ++i)
            *(float2*)(sb + addr[i]) = a[i];
        #pragma unroll
        for (int i = 0; i < 16; ++i) cmbreg[i] = cmbn[i];
        #pragma unroll
        for (int q = 0; q < 4; ++q) gidxr[q] = gidxn[q];
        nwr = nwn; rn = rnn;
    }

    // ---- final pass: reads + gates, measurement straight from registers ----
    float acc = 0.f;
    {
        const int ps = np - 1;
        __syncthreads();
        const unsigned rb = rn << 3;
        #pragma unroll
        for (int i = 0; i < 16; ++i) addr[i] = rb ^ cmbreg[i];
        const uint4* Eb = (const uint4*)((const char*)&pp->pass[ps] + 128);
        uint4 E0 = Eb[0], E1 = Eb[1], E2 = Eb[2], E3 = Eb[3], E4 = Eb[4], E5 = Eb[5];
        const unsigned epm = pp->pass[ps].epm;
        #pragma unroll
        for (int i = 0; i < 16; ++i)
            a[i] = *(const float2*)(sb + addr[i]);
        APPLY_BASIS();
        APPLY_EXTRAS();

        // weight of amp at address rn^cmb_i: sign_w = par(rn&ms_w) ^ fmask_w[i]
        float A[16];
        #pragma unroll
        for (int i = 0; i < 16; ++i) A[i] = 0.f;
        #pragma unroll
        for (int w = 0; w < NQ; ++w) {
            float v = wl[w];
            unsigned p0 = __popc(rn & pp->ms[w]) & 1u;
            float vs = p0 ? -v : v;
            const unsigned fm = pp->fmask[w];
            #pragma unroll
            for (int i = 0; i < 16; ++i)
                A[i] += ((fm >> i) & 1u) ? -vs : vs;
        }
        #pragma unroll
        for (int i = 0; i < 16; ++i)
            acc = fmaf(fmaf(a[i].x, a[i].x, a[i].y * a[i].y), A[i], acc);
    }

    #pragma unroll
    for (int off = 32; off > 0; off >>= 1) acc += __shfl_down(acc, off, 64);
    if ((tid & 63) == 0) red[tid >> 6] = acc;
    __syncthreads();
    if (tid == 0) {
        float s2 = 0.f;
        #pragma unroll
        for (int i = 0; i < NWAVES; ++i) s2 += red[i];
        out[b] = s2 + bl[0];
    }
}

// ---- host-side GF(2) helpers ----
struct GF2Basis {
    unsigned piv[NQ];
    GF2Basis() { for (int i = 0; i < NQ; ++i) piv[i] = 0; }
    bool insert(unsigned v) {            // true iff rank increased
        for (int bb = NQ - 1; bb >= 0; --bb) {
            if (!((v >> bb) & 1)) continue;
            if (piv[bb]) v ^= piv[bb];
            else { piv[bb] = v; return true; }
        }
        return false;
    }
};

static inline int par16(unsigned v) { return __builtin_parity(v); }
static inline unsigned lcg_next(unsigned& s) { s = s * 1664525u + 1013904223u; return s >> 8; }

static unsigned gf_apply(const unsigned* C, unsigned v) {
    unsigned r = 0;
    while (v) { int j = __builtin_ctz(v); v &= v - 1; r ^= C[j]; }
    return r;
}

// C = columns of sigma; on success Ci = columns of sigma^{-1}
static bool gf_invert(const unsigned* C, unsigned* Ci) {
    unsigned rows[NQ], irows[NQ];
    for (int i = 0; i < NQ; ++i) {
        unsigned r = 0;
        for (int j = 0; j < NQ; ++j) r |= ((C[j] >> i) & 1u) << j;
        rows[i] = r; irows[i] = 1u << i;
    }
    for (int c = 0; c < NQ; ++c) {
        int p = -1;
        for (int r = c; r < NQ; ++r) if ((rows[r] >> c) & 1u) { p = r; break; }
        if (p < 0) return false;
        unsigned t = rows[p]; rows[p] = rows[c]; rows[c] = t;
        t = irows[p]; irows[p] = irows[c]; irows[c] = t;
        for (int r = 0; r < NQ; ++r)
            if (r != c && ((rows[r] >> c) & 1u)) { rows[r] ^= rows[c]; irows[r] ^= irows[c]; }
    }
    for (int j = 0; j < NQ; ++j) {
        unsigned col = 0;
        for (int i = 0; i < NQ; ++i) col |= ((irows[i] >> j) & 1u) << i;
        Ci[j] = col;
    }
    return true;
}

extern "C" void kernel_launch(void* const* d_in, const int* in_sizes, int n_in,
                              void* d_out, int out_size, void* d_ws, size_t ws_size,
                              hipStream_t stream) {
    const float* x  = (const float*)d_in[0];   // (B, 14)
    const float* qw = (const float*)d_in[1];   // (3, 14, 3)
    const float* wl = (const float*)d_in[2];   // (1, 14)
    const float* bl = (const float*)d_in[3];   // (1,)
    float* out = (float*)d_out;                // (B, 1)

    const int B = in_sizes[0] / NQ;

    // slot menu: combo value per extra slot (must match device APPLY_EXTRAS)
    static const int EXC[NEX] = {3, 5, 6, 9, 10, 12, 7, 11, 13, 14, 15};
    int c2s[16]; for (int i = 0; i < 16; ++i) c2s[i] = -1;
    for (int k = 0; k < NEX; ++k) c2s[EXC[k]] = k;

    // ---- build gate list (LAYERS 1-2 ONLY; layer 0 = analytic init) in
    // circuit order with (s,m) captured per gate. Rings (incl. layer 0's)
    // are folded into the frame in circuit order.
    unsigned gs[NL * NQ], gm[NL * NQ];
    int ggi[NL * NQ];
    unsigned s[NQ], m[NQ], msIdx[NQ];
    for (int w = 0; w < NQ; ++w) s[w] = m[w] = 1u << (NQ - 1 - w); // wire 0 = MSB
    int ng = 0;
    for (int l = 0; l < NL; ++l) {
        if (l > 0) {
            for (int w = 0; w < NQ; ++w) {
                gs[ng] = s[w]; gm[ng] = m[w]; ggi[ng] = l * NQ + w; ++ng;
            }
        }
        int r = (l % (NQ - 1)) + 1;            // PennyLane ranges: 1,2,3
        for (int w = 0; w < NQ; ++w) {         // CNOT ring: control w, target (w+r)%NQ
            int c = w, t = (w + r) % NQ;
            s[t] ^= s[c];
            m[c] ^= m[t];
        }
    }
    for (int w = 0; w < NQ; ++w) msIdx[w] = s[w];

    struct Raw {
        unsigned rv[10], cmb[16];
        unsigned char gidx[4], nw;
        int exgate[NEX];          // gbuf index or -1
        unsigned exsel[NEX];      // selector (index space)
        unsigned exT[NEX];        // 4-bit basis-parity vector
    } raw[MAXP];
    for (int p = 0; p < MAXP; ++p)
        for (int k = 0; k < NEX; ++k) raw[p].exgate[k] = -1;

    // ---- entry 0: init group aligned to wires 10..13 (index space units) ----
    {
        unsigned mm[4];
        for (int q = 0; q < 4; ++q) mm[q] = 1u << (3 - q);    // wire 10+q
        for (int j = 0; j < 10; ++j) raw[0].rv[j] = 1u << (13 - j); // wires 0..9
        for (int idx = 0; idx < 16; ++idx) {
            unsigned c = 0;
            for (int q = 0; q < 4; ++q) if ((idx >> q) & 1) c ^= mm[q];
            raw[0].cmb[idx] = c;
        }
        for (int q = 0; q < 4; ++q) raw[0].gidx[q] = 0;
        raw[0].nw = 0;
    }

    // ---- greedy pack the 28 gates into passes (cross-layer mixing) ----
    // Basis gates (unit combos): biorthogonal + commute-with-skipped +
    // independent masks. Extras (span-member combos): applied AFTER the
    // basis in the same LDS round trip; accepted iff they commute with
    // already-accepted extras, with later-in-circuit in-pass basis gates,
    // and with all earlier-in-circuit unapplied gates.
    bool used[NL * NQ] = {false};
    int np = 1, remaining = ng;
    while (remaining > 0 && np < MAXP) {
        unsigned pss[4], pmm[4];
        int pgi[4], nw = 0;
        GF2Basis gf;
        for (int g = 0; g < ng && nw < 4; ++g) {
            if (used[g]) continue;
            bool ok = true;
            for (int k = 0; k < nw && ok; ++k)
                if (par16(gs[g] & pmm[k]) || par16(pss[k] & gm[g])) ok = false;
            for (int h = 0; h < g && ok; ++h)
                if (!used[h] && (par16(gs[g] & gm[h]) || par16(gs[h] & gm[g]))) ok = false;
            if (!ok) continue;
            GF2Basis trial = gf;
            if (!trial.insert(gm[g])) continue;
            gf = trial;
            pss[nw] = gs[g]; pmm[nw] = gm[g]; pgi[nw] = g; ++nw;
            used[g] = true; --remaining;
        }
        // pad to 4 independent masks; normalize pads so they don't flip the
        // real wires' logical bits
        unsigned mm[4], ss[4];
        for (int i = 0; i < nw; ++i) { mm[i] = pmm[i]; ss[i] = pss[i]; }
        for (int i = nw; i < 4; ++i) {
            unsigned cand = 0;
            for (int t = 0; t < NQ; ++t)
                if (gf.insert(1u << t)) { cand = 1u << t; break; }
            for (int j = 0; j < nw; ++j)
                if (par16(cand & ss[j])) cand ^= mm[j];
            mm[i] = cand; ss[i] = 0;
        }
        // complement basis (10 vecs), normalized to zero logical bits
        int nR = 0;
        for (int t = 0; t < NQ && nR < 10; ++t) {
            if (gf.insert(1u << t)) {
                unsigned v = 1u << t;
                for (int j = 0; j < nw; ++j)
                    if (par16(v & ss[j])) v ^= mm[j];
                raw[np].rv[nR++] = v;
            }
        }
        for (int idx = 0; idx < 16; ++idx) {
            unsigned c = 0;
            for (int q = 0; q < 4; ++q) if ((idx >> q) & 1) c ^= mm[q];
            raw[np].cmb[idx] = c;
        }
        for (int q = 0; q < 4; ++q)
            raw[np].gidx[q] = (unsigned char)(q < nw ? ggi[pgi[q]] : 0);
        raw[np].nw = (unsigned char)nw;

        // ---- extras sweep: span-member gates in circuit order ----
        {
            int exCirc[NEX]; int nExtra = 0;
            for (int g = 0; g < ng; ++g) {
                if (used[g]) continue;
                int c = -1;
                for (int t2 = 3; t2 < 16; ++t2) {
                    if (__builtin_popcount((unsigned)t2) < 2) continue;
                    unsigned xr = 0;
                    for (int j = 0; j < 4; ++j) if ((t2 >> j) & 1) xr ^= mm[j];
                    if (xr == gm[g]) { c = t2; break; }
                }
                if (c < 0) continue;
                int slot = c2s[c];
                if (slot < 0 || raw[np].exgate[slot] >= 0) continue;
                // T = basis-parity vector; parity of T over combo bits must
                // be 1 (duality invariant; checked as a sanity filter)
                unsigned T = 0;
                for (int j = 0; j < 4; ++j)
                    T |= (unsigned)(par16(mm[j] & gs[g]) & 1) << j;
                {
                    int sp = 0;
                    for (int j = 0; j < 4; ++j) if ((c >> j) & 1) sp ^= (T >> j) & 1;
                    if (!sp) continue;
                }
                bool ok = true;
                for (int e = 0; e < nExtra && ok; ++e) {
                    int h = exCirc[e];
                    if (par16(gs[g] & gm[h]) || par16(gs[h] & gm[g])) ok = false;
                }
                for (int kk = 0; kk < nw && ok; ++kk) {
                    int h = pgi[kk];
                    if (h > g && (par16(gs[g] & gm[h]) || par16(gs[h] & gm[g]))) ok = false;
                }
                for (int h = 0; h < g && ok; ++h)
                    if (!used[h] && (par16(gs[g] & gm[h]) || par16(gs[h] & gm[g]))) ok = false;
                if (!ok) continue;
                raw[np].exgate[slot] = ggi[g];
                raw[np].exsel[slot] = gs[g];
                raw[np].exT[slot] = T;
                exCirc[nExtra++] = g;
                used[g] = true; --remaining;
            }
        }
        ++np;
    }

    // ---- choose layout sigma: every entry's rep space (incl. init) must
    // project with full rank 4 onto the bank-pair bits (addr mod 16) ----
    unsigned Cm[NQ], Ci[NQ];
    unsigned seed = 0x9E3779B9u;
    bool found = false;
    for (int tries = 0; tries < 5000 && !found; ++tries) {
        for (int j = 0; j < NQ; ++j) Cm[j] = lcg_next(seed) & (NSTATE - 1);
        if (!gf_invert(Cm, Ci)) continue;
        found = true;
        for (int p = 0; p < np && found; ++p) {
            unsigned piv[4] = {0, 0, 0, 0}; int npv = 0;
            for (int i = 0; i < 10; ++i) {
                unsigned w2 = gf_apply(Cm, raw[p].rv[i]);
                for (int bb = 0; bb < 4; ++bb)
                    if (((w2 >> bb) & 1u) && piv[bb]) w2 ^= piv[bb];
                if ((w2 & 15u) && npv < 4) { piv[__builtin_ctz(w2 & 15u)] = w2; ++npv; }
            }
            if (npv < 4) found = false;
        }
    }
    if (!found) {  // fallback: identity layout (correct, just slower)
        for (int j = 0; j < NQ; ++j) Cm[j] = 1u << j;
        gf_invert(Cm, Ci);
    }

    // ---- emit device params in ADDRESS space into the global table ----
    static ParamsG h_pg;                // static: stable across graph replays
    memset(&h_pg, 0, sizeof(h_pg));
    for (int p = 0; p < np; ++p) {
        unsigned u[10];
        for (int i = 0; i < 10; ++i) u[i] = gf_apply(Cm, raw[p].rv[i]);
        // order: 4 bank-pivot vectors first (they cover lane bits 0..3)
        unsigned piv[4] = {0, 0, 0, 0};
        int ord[10], npv = 0, rest[10], nrest = 0;
        for (int i = 0; i < 10; ++i) {
            unsigned w2 = u[i];
            for (int bb = 0; bb < 4; ++bb)
                if (((w2 >> bb) & 1u) && piv[bb]) w2 ^= piv[bb];
            if ((w2 & 15u) && npv < 4) { piv[__builtin_ctz(w2 & 15u)] = w2; ord[npv++] = i; }
            else rest[nrest++] = i;
        }
        int kk = 0;
        for (int i = 0; i < npv; ++i) h_pg.pass[p].R[kk++] = u[ord[i]];
        for (int i = 0; i < nrest; ++i) h_pg.pass[p].R[kk++] = u[rest[i]];
        for (int idx = 0; idx < 16; ++idx)
            h_pg.pass[p].cmb8[idx] = gf_apply(Cm, raw[p].cmb[idx]) << 3;
        for (int q = 0; q < 4; ++q) h_pg.pass[p].gidx[q] = raw[p].gidx[q];
        h_pg.pass[p].nw = raw[p].nw;
        // extras: sga = sigma^{-T}(s_g); parw[i] = popc(i & T) & 1
        unsigned epm = 0;
        for (int k = 0; k < NEX; ++k) {
            if (raw[p].exgate[k] < 0) continue;
            epm |= 1u << k;
            unsigned sga = 0;
            for (int i = 0; i < NQ; ++i)
                sga |= (unsigned)(par16(Ci[i] & raw[p].exsel[k]) & 1) << i;
            h_pg.pass[p].eg[k] = sga | ((unsigned)raw[p].exgate[k] << 16);
            unsigned T = raw[p].exT[k], pw = 0;
            for (int i = 0; i < 16; ++i)
                pw |= (unsigned)(__builtin_popcount(i & T) & 1) << i;
            h_pg.pass[p].parw[k] = pw;
        }
        h_pg.pass[p].epm = epm;
    }
    // measurement masks: par(sigma^{-1}(t) & ms) = par(t & sigma^{-T} ms)
    for (int w = 0; w < NQ; ++w) {
        unsigned msp = 0;
        for (int i = 0; i < NQ; ++i)
            msp |= (unsigned)(par16(Ci[i] & msIdx[w]) & 1) << i;
        h_pg.ms[w] = msp;
    }
    // combo-part parities of the FINAL pass (measurement runs from registers;
    // cmb8 is pre-shifted, ms is in address space -> compare unshifted)
    for (int w = 0; w < NQ; ++w) {
        unsigned fm = 0;
        for (int i = 0; i < 16; ++i)
            fm |= (unsigned)(par16((h_pg.pass[np - 1].cmb8[i] >> 3) & h_pg.ms[w]) & 1) << i;
        h_pg.fmask[w] = fm;
    }
    // init physical-bit tables: bit_w(sigma^{-1}(a)) = par(a & t_w), with
    // t_w = sigma^{-T}(unit of wire w); IW[j] packs par(R0[j] & t_w) at bit w.
    {
        unsigned tmask[NQ];
        for (int w = 0; w < NQ; ++w) {
            unsigned t = 0;
            for (int i = 0; i < NQ; ++i)
                t |= (unsigned)((Ci[i] >> (NQ - 1 - w)) & 1u) << i;
            tmask[w] = t;
        }
        for (int j = 0; j < 10; ++j) {
            unsigned iw = 0;
            for (int w = 0; w < NQ; ++w)
                iw |= (unsigned)(par16(h_pg.pass[0].R[j] & tmask[w]) & 1) << w;
            h_pg.initIW[j] = iw;
        }
    }

    ParamsG* d_pg = (ParamsG*)d_ws;
    hipMemcpyAsync(d_pg, &h_pg, sizeof(ParamsG), hipMemcpyHostToDevice, stream);
    qsim_kernel<<<dim3(B), dim3(BT), 0, stream>>>(x, qw, wl, bl, out, d_pg, np);
}

// Round 10
// 100.553 us; speedup vs baseline: 1.0218x; 1.0204x over previous
//
#include <hip/hip_runtime.h>
#include <string.h>

#define NQ 14
#define NSTATE (1 << NQ)       // 16384 amplitudes
#define NL 3
#define MAXP 12                // max table entries (init + gate passes)
#define BT 1024                // threads per block
#define NWAVES (BT / 64)
#define NEX 11                 // extra-gate combo menu size

// Lazily-permuted simulation: CNOT rings folded into GF(2) index maps, and a
// global GF(2)-linear LDS layout sigma (amp p stored at address sigma(p)).
// sigma is chosen host-side so that EVERY pass's representative space
// projects with full rank 4 onto the bank-pair bits (addr mod 16).
// Verified structure: analytic product-state init for layer 0, fused
// measurement, scalar float2 complex math, span-closure extras (8 gates
// absorbed -> 5 gate passes).
// This round's single change: the ENTIRE param table lives in LDS (psh),
// copied once at kernel start. Round 7 proved the compiler pins VGPR at 52
// regardless of budget and sinks the per-pass extras-table GLOBAL loads to
// their use point, exposing ~1.6us of vmcnt latency per extra gate on the
// critical path. LDS param reads are wave-uniform broadcasts (conflict-free,
// lgkm-domain, ~low latency), so re-reading at use is nearly free and the
// register-residency question disappears.
struct PassG {
    unsigned cmb8[16];   // 0   XOR combos of pair masks, pre-shifted <<3
    unsigned R[10];      // 64  complement-basis images (tid -> rep)
    unsigned gidx[4];    // 104 basis gate table indices
    unsigned nw;         // 120 real basis gates in this pass
    unsigned epm;        // 124 extra-present mask (bit k = slot k active)
    unsigned eg[11];     // 128 sga(14b) | gidx<<16
    unsigned parw[11];   // 172 orientation parity words (bit i = par(i&T))
    unsigned pad[2];     // 216 -> 224 B
};
struct ParamsG {
    PassG pass[MAXP];
    unsigned ms[NQ];      // final Z_w selector masks (address space)
    unsigned fmask[NQ];   // bit i = par(cmb_last[i] & ms[w])
    unsigned initIW[10];  // bit w = physical-bit_w contribution of R0[j]
};
#define PG_WORDS ((int)(sizeof(ParamsG) / 4))

struct C2x2 { float2 m[2][2]; };

__device__ __forceinline__ float2 cmul(float2 a, float2 b) {
    return make_float2(a.x * b.x - a.y * b.y, a.x * b.y + a.y * b.x);
}
__device__ __forceinline__ float2 cmac(float2 acc, float2 a, float2 b) {
    acc.x = fmaf(a.x, b.x, fmaf(-a.y, b.y, acc.x));
    acc.y = fmaf(a.x, b.y, fmaf(a.y, b.x, acc.y));
    return acc;
}

// PennyLane Rot(phi,theta,omega) = RZ(omega) RY(theta) RZ(phi)
__device__ __forceinline__ C2x2 rot_gate(const float* qp) {
    float phi = qp[0], th = qp[1], om = qp[2];
    float ct, stt; __sincosf(0.5f * th, &stt, &ct);
    float sa, ca; __sincosf(0.5f * (phi + om), &sa, &ca);
    float sb, cb; __sincosf(0.5f * (phi - om), &sb, &cb);
    C2x2 G;
    G.m[0][0] = make_float2(ca * ct, -sa * ct);
    G.m[0][1] = make_float2(-cb * stt, -sb * stt);
    G.m[1][0] = make_float2(cb * stt, -sb * stt);
    G.m[1][1] = make_float2(ca * ct, sa * ct);
    return G;
}

// G := G * RX(ang)   (RX applied first to the state)
__device__ __forceinline__ C2x2 fuse_rx(C2x2 G, float ang) {
    float sh, ch; __sincosf(0.5f * ang, &sh, &ch);
    float2 c = make_float2(ch, 0.f), is = make_float2(0.f, -sh);
    C2x2 R;
    #pragma unroll
    for (int i = 0; i < 2; ++i) {
        R.m[i][0] = cmac(cmul(G.m[i][0], c), G.m[i][1], is);
        R.m[i][1] = cmac(cmul(G.m[i][1], c), G.m[i][0], is);
    }
    return R;
}

// apply one span-member ("extra") gate: pairs (i, i^C); per-pair orientation
// bit = par(s_g & rep) ^ par(s_g & cmb_i) = og ^ parw[i]; all register
// indices compile-time (rule #20).
template<int C>
__device__ __forceinline__ void apply_extra(float2 a[16], const float2* gb,
        unsigned w1, unsigned pw, unsigned rep)
{
    const unsigned sga = w1 & 0x3FFFu;
    const int gi = (int)(w1 >> 16) * 4;
    const unsigned og = __popc(rep & sga) & 1u;
    const unsigned swv = pw ^ (og ? 0xFFFFu : 0u);
    float2 g00 = gb[gi + 0], g01 = gb[gi + 1], g10 = gb[gi + 2], g11 = gb[gi + 3];
    const int LB = C & (-C);
    #pragma unroll
    for (int i = 0; i < 16; ++i) {
        if (!(i & LB)) {
            const int i1 = i ^ C;
            const bool sw = (swv >> i) & 1u;
            float2 x0 = sw ? a[i1] : a[i];
            float2 x1 = sw ? a[i]  : a[i1];
            float2 n0 = cmac(cmul(g00, x0), g01, x1);
            float2 n1 = cmac(cmul(g10, x0), g11, x1);
            a[i]  = sw ? n1 : n0;
            a[i1] = sw ? n0 : n1;
        }
    }
}

// basis gates: unit combos, orientation = logical bit q; params read from LDS
#define APPLY_BASIS(PS)                                                     \
    {                                                                       \
        _Pragma("unroll")                                                   \
        for (int q = 0; q < 4; ++q) {                                       \
            if (q < (int)nwr) {    /* wave-uniform branch */                \
                const int gi = (int)psh.pass[PS].gidx[q] * 4;               \
                float2 g00 = gbuf[gi + 0], g01 = gbuf[gi + 1];              \
                float2 g10 = gbuf[gi + 2], g11 = gbuf[gi + 3];              \
                _Pragma("unroll")                                           \
                for (int i = 0; i < 16; ++i) {                              \
                    if (!((i >> q) & 1)) {                                  \
                        const int i1 = i | (1 << q);                        \
                        float2 a0 = a[i], a1 = a[i1];                       \
                        float2 n0 = cmac(cmul(g00, a0), g01, a1);           \
                        float2 n1 = cmac(cmul(g10, a0), g11, a1);           \
                        a[i] = n0; a[i1] = n1;                              \
                    }                                                       \
                }                                                           \
            }                                                               \
        }                                                                   \
    }

// extras: eg/parw read from LDS at use (wave-uniform broadcast, near-free)
#define APPLY_EXTRAS(PS)                                                    \
    {                                                                       \
        if (epm) {                                                          \
            if (epm & (1u<<0))  apply_extra<3> (a, gbuf, psh.pass[PS].eg[0],  psh.pass[PS].parw[0],  rn); \
            if (epm & (1u<<1))  apply_extra<5> (a, gbuf, psh.pass[PS].eg[1],  psh.pass[PS].parw[1],  rn); \
            if (epm & (1u<<2))  apply_extra<6> (a, gbuf, psh.pass[PS].eg[2],  psh.pass[PS].parw[2],  rn); \
            if (epm & (1u<<3))  apply_extra<9> (a, gbuf, psh.pass[PS].eg[3],  psh.pass[PS].parw[3],  rn); \
            if (epm & (1u<<4))  apply_extra<10>(a, gbuf, psh.pass[PS].eg[4],  psh.pass[PS].parw[4],  rn); \
            if (epm & (1u<<5))  apply_extra<12>(a, gbuf, psh.pass[PS].eg[5],  psh.pass[PS].parw[5],  rn); \
            if (epm & (1u<<6))  apply_extra<7> (a, gbuf, psh.pass[PS].eg[6],  psh.pass[PS].parw[6],  rn); \
            if (epm & (1u<<7))  apply_extra<11>(a, gbuf, psh.pass[PS].eg[7],  psh.pass[PS].parw[7],  rn); \
            if (epm & (1u<<8))  apply_extra<13>(a, gbuf, psh.pass[PS].eg[8],  psh.pass[PS].parw[8],  rn); \
            if (epm & (1u<<9))  apply_extra<14>(a, gbuf, psh.pass[PS].eg[9],  psh.pass[PS].parw[9],  rn); \
            if (epm & (1u<<10)) apply_extra<15>(a, gbuf, psh.pass[PS].eg[10], psh.pass[PS].parw[10], rn); \
        }                                                                   \
    }

__global__ __launch_bounds__(BT, 4) void qsim_kernel(
    const float* __restrict__ x, const float* __restrict__ qw,
    const float* __restrict__ wl, const float* __restrict__ bl,
    float* __restrict__ out, const ParamsG* __restrict__ pp, int np)
{
    __shared__ float2 st[NSTATE];          // 128 KB state
    __shared__ float2 gbuf[NL * NQ * 4];   // 42 precomputed 2x2 gates
    __shared__ float2 ubuf[NQ][2];         // per-wire layer-0 2-vectors u_w
    __shared__ float red[NWAVES];
    __shared__ __align__(16) ParamsG psh;  // 2.8 KB param table in LDS

    const int tid = threadIdx.x;
    const int b = blockIdx.x;

    // stage the whole param table into LDS once (coalesced global reads)
    {
        const unsigned* srcw = (const unsigned*)pp;
        unsigned* dstw = (unsigned*)&psh;
        for (int i = tid; i < PG_WORDS; i += BT) dstw[i] = srcw[i];
    }

    // precompute all 2x2 gates once (layer 0 fuses the RX embedding);
    // layer-0 gates additionally publish u_w = G*(1,0)^T for the init
    if (tid < NL * NQ) {
        int l = tid / NQ, w = tid % NQ;
        C2x2 G = rot_gate(qw + tid * 3);
        if (l == 0) {
            G = fuse_rx(G, x[b * NQ + w]);
            ubuf[w][0] = G.m[0][0];
            ubuf[w][1] = G.m[1][0];
        }
        gbuf[tid * 4 + 0] = G.m[0][0];
        gbuf[tid * 4 + 1] = G.m[0][1];
        gbuf[tid * 4 + 2] = G.m[1][0];
        gbuf[tid * 4 + 3] = G.m[1][1];
    }

    char* sb = (char*)st;
    float2 a[16];
    unsigned addr[16];
    unsigned rn;

    __syncthreads();   // gbuf + ubuf + psh ready

    // ---- pass 0: analytic product-state init (layer 0 never entangles) ----
    // amp(rep ^ cmb_i) = [prod_{w=0..9} u_w[bit_w(rep)]] * prod_q u_{10+q}[i_q]
    {
        unsigned r0 = 0, b0 = 0;
        #pragma unroll
        for (int j = 0; j < 10; ++j) {
            const unsigned sel = (tid >> j) & 1;
            r0 ^= sel ? psh.pass[0].R[j] : 0u;
            b0 ^= sel ? psh.initIW[j] : 0u;
        }
        rn = r0;
        const unsigned rb = rn << 3;
        float2 c = ubuf[0][b0 & 1];
        #pragma unroll
        for (int w = 1; w < 10; ++w)
            c = cmul(c, ubuf[w][(b0 >> w) & 1]);
        a[0] = cmul(c, ubuf[10][0]);
        a[1] = cmul(c, ubuf[10][1]);
        #pragma unroll
        for (int i = 0; i < 2; ++i) {
            a[2 + i] = cmul(a[i], ubuf[11][1]);
            a[i]     = cmul(a[i], ubuf[11][0]);
        }
        #pragma unroll
        for (int i = 0; i < 4; ++i) {
            a[4 + i] = cmul(a[i], ubuf[12][1]);
            a[i]     = cmul(a[i], ubuf[12][0]);
        }
        #pragma unroll
        for (int i = 0; i < 8; ++i) {
            a[8 + i] = cmul(a[i], ubuf[13][1]);
            a[i]     = cmul(a[i], ubuf[13][0]);
        }
        #pragma unroll
        for (int i = 0; i < 16; ++i)
            *(float2*)(sb + (rb ^ psh.pass[0].cmb8[i])) = a[i];  // state init
    }

    // pipeline: rep value for pass 1 (LDS reads, off the post-barrier path)
    {
        unsigned rt = 0;
        #pragma unroll
        for (int j = 0; j < 10; ++j)
            rt ^= ((tid >> j) & 1) ? psh.pass[1].R[j] : 0u;
        rn = rt;
    }

    #pragma unroll 1
    for (int ps = 1; ps < np - 1; ++ps) {
        __syncthreads();   // previous pass's writes visible
        const unsigned rb = rn << 3;
        #pragma unroll
        for (int i = 0; i < 16; ++i) addr[i] = rb ^ psh.pass[ps].cmb8[i];
        #pragma unroll
        for (int i = 0; i < 16; ++i)
            a[i] = *(const float2*)(sb + addr[i]);
        // next pass's rep during this pass's compute (cheap LDS broadcasts)
        unsigned rt = 0;
        #pragma unroll
        for (int j = 0; j < 10; ++j)
            rt ^= ((tid >> j) & 1) ? psh.pass[ps + 1].R[j] : 0u;
        const unsigned nwr = psh.pass[ps].nw;
        APPLY_BASIS(ps);
        const unsigned epm = psh.pass[ps].epm;
        APPLY_EXTRAS(ps);
        #pragma unroll
        for (int i = 0; i < 16; ++i)
            *(float2*)(sb + addr[i]) = a[i];
        rn = rt;
    }

    // ---- final pass: reads + gates, measurement straight from registers ----
    float acc = 0.f;
    {
        const int ps = np - 1;
        __syncthreads();
        const unsigned rb = rn << 3;
        #pragma unroll
        for (int i = 0; i < 16; ++i) addr[i] = rb ^ psh.pass[ps].cmb8[i];
        #pragma unroll
        for (int i = 0; i < 16; ++i)
            a[i] = *(const float2*)(sb + addr[i]);
        const unsigned nwr = psh.pass[ps].nw;
        APPLY_BASIS(ps);
        const unsigned epm = psh.pass[ps].epm;
        APPLY_EXTRAS(ps);

        // weight of amp at address rn^cmb_i: sign_w = par(rn&ms_w) ^ fmask_w[i]
        float A[16];
        #pragma unroll
        for (int i = 0; i < 16; ++i) A[i] = 0.f;
        #pragma unroll
        for (int w = 0; w < NQ; ++w) {
            float v = wl[w];
            unsigned p0 = __popc(rn & psh.ms[w]) & 1u;
            float vs = p0 ? -v : v;
            const unsigned fm = psh.fmask[w];
            #pragma unroll
            for (int i = 0; i < 16; ++i)
                A[i] += ((fm >> i) & 1u) ? -vs : vs;
        }
        #pragma unroll
        for (int i = 0; i < 16; ++i)
            acc = fmaf(fmaf(a[i].x, a[i].x, a[i].y * a[i].y), A[i], acc);
    }

    #pragma unroll
    for (int off = 32; off > 0; off >>= 1) acc += __shfl_down(acc, off, 64);
    if ((tid & 63) == 0) red[tid >> 6] = acc;
    __syncthreads();
    if (tid == 0) {
        float s2 = 0.f;
        #pragma unroll
        for (int i = 0; i < NWAVES; ++i) s2 += red[i];
        out[b] = s2 + bl[0];
    }
}

// ---- host-side GF(2) helpers ----
struct GF2Basis {
    unsigned piv[NQ];
    GF2Basis() { for (int i = 0; i < NQ; ++i) piv[i] = 0; }
    bool insert(unsigned v) {            // true iff rank increased
        for (int bb = NQ - 1; bb >= 0; --bb) {
            if (!((v >> bb) & 1)) continue;
            if (piv[bb]) v ^= piv[bb];
            else { piv[bb] = v; return true; }
        }
        return false;
    }
};

static inline int par16(unsigned v) { return __builtin_parity(v); }
static inline unsigned lcg_next(unsigned& s) { s = s * 1664525u + 1013904223u; return s >> 8; }

static unsigned gf_apply(const unsigned* C, unsigned v) {
    unsigned r = 0;
    while (v) { int j = __builtin_ctz(v); v &= v - 1; r ^= C[j]; }
    return r;
}

// C = columns of sigma; on success Ci = columns of sigma^{-1}
static bool gf_invert(const unsigned* C, unsigned* Ci) {
    unsigned rows[NQ], irows[NQ];
    for (int i = 0; i < NQ; ++i) {
        unsigned r = 0;
        for (int j = 0; j < NQ; ++j) r |= ((C[j] >> i) & 1u) << j;
        rows[i] = r; irows[i] = 1u << i;
    }
    for (int c = 0; c < NQ; ++c) {
        int p = -1;
        for (int r = c; r < NQ; ++r) if ((rows[r] >> c) & 1u) { p = r; break; }
        if (p < 0) return false;
        unsigned t = rows[p]; rows[p] = rows[c]; rows[c] = t;
        t = irows[p]; irows[p] = irows[c]; irows[c] = t;
        for (int r = 0; r < NQ; ++r)
            if (r != c && ((rows[r] >> c) & 1u)) { rows[r] ^= rows[c]; irows[r] ^= irows[c]; }
    }
    for (int j = 0; j < NQ; ++j) {
        unsigned col = 0;
        for (int i = 0; i < NQ; ++i) col |= ((irows[i] >> j) & 1u) << i;
        Ci[j] = col;
    }
    return true;
}

extern "C" void kernel_launch(void* const* d_in, const int* in_sizes, int n_in,
                              void* d_out, int out_size, void* d_ws, size_t ws_size,
                              hipStream_t stream) {
    const float* x  = (const float*)d_in[0];   // (B, 14)
    const float* qw = (const float*)d_in[1];   // (3, 14, 3)
    const float* wl = (const float*)d_in[2];   // (1, 14)
    const float* bl = (const float*)d_in[3];   // (1,)
    float* out = (float*)d_out;                // (B, 1)

    const int B = in_sizes[0] / NQ;

    // slot menu: combo value per extra slot (must match device APPLY_EXTRAS)
    static const int EXC[NEX] = {3, 5, 6, 9, 10, 12, 7, 11, 13, 14, 15};
    int c2s[16]; for (int i = 0; i < 16; ++i) c2s[i] = -1;
    for (int k = 0; k < NEX; ++k) c2s[EXC[k]] = k;

    // ---- build gate list (LAYERS 1-2 ONLY; layer 0 = analytic init) in
    // circuit order with (s,m) captured per gate. Rings (incl. layer 0's)
    // are folded into the frame in circuit order.
    unsigned gs[NL * NQ], gm[NL * NQ];
    int ggi[NL * NQ];
    unsigned s[NQ], m[NQ], msIdx[NQ];
    for (int w = 0; w < NQ; ++w) s[w] = m[w] = 1u << (NQ - 1 - w); // wire 0 = MSB
    int ng = 0;
    for (int l = 0; l < NL; ++l) {
        if (l > 0) {
            for (int w = 0; w < NQ; ++w) {
                gs[ng] = s[w]; gm[ng] = m[w]; ggi[ng] = l * NQ + w; ++ng;
            }
        }
        int r = (l % (NQ - 1)) + 1;            // PennyLane ranges: 1,2,3
        for (int w = 0; w < NQ; ++w) {         // CNOT ring: control w, target (w+r)%NQ
            int c = w, t = (w + r) % NQ;
            s[t] ^= s[c];
            m[c] ^= m[t];
        }
    }
    for (int w = 0; w < NQ; ++w) msIdx[w] = s[w];

    struct Raw {
        unsigned rv[10], cmb[16];
        unsigned char gidx[4], nw;
        int exgate[NEX];          // gbuf index or -1
        unsigned exsel[NEX];      // selector (index space)
        unsigned exT[NEX];        // 4-bit basis-parity vector
    } raw[MAXP];
    for (int p = 0; p < MAXP; ++p)
        for (int k = 0; k < NEX; ++k) raw[p].exgate[k] = -1;

    // ---- entry 0: init group aligned to wires 10..13 (index space units) ----
    {
        unsigned mm[4];
        for (int q = 0; q < 4; ++q) mm[q] = 1u << (3 - q);    // wire 10+q
        for (int j = 0; j < 10; ++j) raw[0].rv[j] = 1u << (13 - j); // wires 0..9
        for (int idx = 0; idx < 16; ++idx) {
            unsigned c = 0;
            for (int q = 0; q < 4; ++q) if ((idx >> q) & 1) c ^= mm[q];
            raw[0].cmb[idx] = c;
        }
        for (int q = 0; q < 4; ++q) raw[0].gidx[q] = 0;
        raw[0].nw = 0;
    }

    // ---- greedy pack the 28 gates into passes (cross-layer mixing) ----
    // Basis gates (unit combos): biorthogonal + commute-with-skipped +
    // independent masks. Extras (span-member combos): applied AFTER the
    // basis in the same LDS round trip; accepted iff they commute with
    // already-accepted extras, with later-in-circuit in-pass basis gates,
    // and with all earlier-in-circuit unapplied gates.
    bool used[NL * NQ] = {false};
    int np = 1, remaining = ng;
    while (remaining > 0 && np < MAXP) {
        unsigned pss[4], pmm[4];
        int pgi[4], nw = 0;
        GF2Basis gf;
        for (int g = 0; g < ng && nw < 4; ++g) {
            if (used[g]) continue;
            bool ok = true;
            for (int k = 0; k < nw && ok; ++k)
                if (par16(gs[g] & pmm[k]) || par16(pss[k] & gm[g])) ok = false;
            for (int h = 0; h < g && ok; ++h)
                if (!used[h] && (par16(gs[g] & gm[h]) || par16(gs[h] & gm[g]))) ok = false;
            if (!ok) continue;
            GF2Basis trial = gf;
            if (!trial.insert(gm[g])) continue;
            gf = trial;
            pss[nw] = gs[g]; pmm[nw] = gm[g]; pgi[nw] = g; ++nw;
            used[g] = true; --remaining;
        }
        // pad to 4 independent masks; normalize pads so they don't flip the
        // real wires' logical bits
        unsigned mm[4], ss[4];
        for (int i = 0; i < nw; ++i) { mm[i] = pmm[i]; ss[i] = pss[i]; }
        for (int i = nw; i < 4; ++i) {
            unsigned cand = 0;
            for (int t = 0; t < NQ; ++t)
                if (gf.insert(1u << t)) { cand = 1u << t; break; }
            for (int j = 0; j < nw; ++j)
                if (par16(cand & ss[j])) cand ^= mm[j];
            mm[i] = cand; ss[i] = 0;
        }
        // complement basis (10 vecs), normalized to zero logical bits
        int nR = 0;
        for (int t = 0; t < NQ && nR < 10; ++t) {
            if (gf.insert(1u << t)) {
                unsigned v = 1u << t;
                for (int j = 0; j < nw; ++j)
                    if (par16(v & ss[j])) v ^= mm[j];
                raw[np].rv[nR++] = v;
            }
        }
        for (int idx = 0; idx < 16; ++idx) {
            unsigned c = 0;
            for (int q = 0; q < 4; ++q) if ((idx >> q) & 1) c ^= mm[q];
            raw[np].cmb[idx] = c;
        }
        for (int q = 0; q < 4; ++q)
            raw[np].gidx[q] = (unsigned char)(q < nw ? ggi[pgi[q]] : 0);
        raw[np].nw = (unsigned char)nw;

        // ---- extras sweep: span-member gates in circuit order ----
        {
            int exCirc[NEX]; int nExtra = 0;
            for (int g = 0; g < ng; ++g) {
                if (used[g]) continue;
                int c = -1;
                for (int t2 = 3; t2 < 16; ++t2) {
                    if (__builtin_popcount((unsigned)t2) < 2) continue;
                    unsigned xr = 0;
                    for (int j = 0; j < 4; ++j) if ((t2 >> j) & 1) xr ^= mm[j];
                    if (xr == gm[g]) { c = t2; break; }
                }
                if (c < 0) continue;
                int slot = c2s[c];
                if (slot < 0 || raw[np].exgate[slot] >= 0) continue;
                // T = basis-parity vector; parity of T over combo bits must
                // be 1 (duality invariant; checked as a sanity filter)
                unsigned T = 0;
                for (int j = 0; j < 4; ++j)
                    T |= (unsigned)(par16(mm[j] & gs[g]) & 1) << j;
                {
                    int sp = 0;
                    for (int j = 0; j < 4; ++j) if ((c >> j) & 1) sp ^= (T >> j) & 1;
                    if (!sp) continue;
                }
                bool ok = true;
                for (int e = 0; e < nExtra && ok; ++e) {
                    int h = exCirc[e];
                    if (par16(gs[g] & gm[h]) || par16(gs[h] & gm[g])) ok = false;
                }
                for (int kk = 0; kk < nw && ok; ++kk) {
                    int h = pgi[kk];
                    if (h > g && (par16(gs[g] & gm[h]) || par16(gs[h] & gm[g]))) ok = false;
                }
                for (int h = 0; h < g && ok; ++h)
                    if (!used[h] && (par16(gs[g] & gm[h]) || par16(gs[h] & gm[g]))) ok = false;
                if (!ok) continue;
                raw[np].exgate[slot] = ggi[g];
                raw[np].exsel[slot] = gs[g];
                raw[np].exT[slot] = T;
                exCirc[nExtra++] = g;
                used[g] = true; --remaining;
            }
        }
        ++np;
    }

    // ---- choose layout sigma: every entry's rep space (incl. init) must
    // project with full rank 4 onto the bank-pair bits (addr mod 16) ----
    unsigned Cm[NQ], Ci[NQ];
    unsigned seed = 0x9E3779B9u;
    bool found = false;
    for (int tries = 0; tries < 5000 && !found; ++tries) {
        for (int j = 0; j < NQ; ++j) Cm[j] = lcg_next(seed) & (NSTATE - 1);
        if (!gf_invert(Cm, Ci)) continue;
        found = true;
        for (int p = 0; p < np && found; ++p) {
            unsigned piv[4] = {0, 0, 0, 0}; int npv = 0;
            for (int i = 0; i < 10; ++i) {
                unsigned w2 = gf_apply(Cm, raw[p].rv[i]);
                for (int bb = 0; bb < 4; ++bb)
                    if (((w2 >> bb) & 1u) && piv[bb]) w2 ^= piv[bb];
                if ((w2 & 15u) && npv < 4) { piv[__builtin_ctz(w2 & 15u)] = w2; ++npv; }
            }
            if (npv < 4) found = false;
        }
    }
    if (!found) {  // fallback: identity layout (correct, just slower)
        for (int j = 0; j < NQ; ++j) Cm[j] = 1u << j;
        gf_invert(Cm, Ci);
    }

    // ---- emit device params in ADDRESS space into the global table ----
    static ParamsG h_pg;                // static: stable across graph replays
    memset(&h_pg, 0, sizeof(h_pg));
    for (int p = 0; p < np; ++p) {
        unsigned u[10];
        for (int i = 0; i < 10; ++i) u[i] = gf_apply(Cm, raw[p].rv[i]);
        // order: 4 bank-pivot vectors first (they cover lane bits 0..3)
        unsigned piv[4] = {0, 0, 0, 0};
        int ord[10], npv = 0, rest[10], nrest = 0;
        for (int i = 0; i < 10; ++i) {
            unsigned w2 = u[i];
            for (int bb = 0; bb < 4; ++bb)
                if (((w2 >> bb) & 1u) && piv[bb]) w2 ^= piv[bb];
            if ((w2 & 15u) && npv < 4) { piv[__builtin_ctz(w2 & 15u)] = w2; ord[npv++] = i; }
            else rest[nrest++] = i;
        }
        int kk = 0;
        for (int i = 0; i < npv; ++i) h_pg.pass[p].R[kk++] = u[ord[i]];
        for (int i = 0; i < nrest; ++i) h_pg.pass[p].R[kk++] = u[rest[i]];
        for (int idx = 0; idx < 16; ++idx)
            h_pg.pass[p].cmb8[idx] = gf_apply(Cm, raw[p].cmb[idx]) << 3;
        for (int q = 0; q < 4; ++q) h_pg.pass[p].gidx[q] = raw[p].gidx[q];
        h_pg.pass[p].nw = raw[p].nw;
        // extras: sga = sigma^{-T}(s_g); parw[i] = popc(i & T) & 1
        unsigned epm = 0;
        for (int k = 0; k < NEX; ++k) {
            if (raw[p].exgate[k] < 0) continue;
            epm |= 1u << k;
            unsigned sga = 0;
            for (int i = 0; i < NQ; ++i)
                sga |= (unsigned)(par16(Ci[i] & raw[p].exsel[k]) & 1) << i;
            h_pg.pass[p].eg[k] = sga | ((unsigned)raw[p].exgate[k] << 16);
            unsigned T = raw[p].exT[k], pw = 0;
            for (int i = 0; i < 16; ++i)
                pw |= (unsigned)(__builtin_popcount(i & T) & 1) << i;
            h_pg.pass[p].parw[k] = pw;
        }
        h_pg.pass[p].epm = epm;
    }
    // measurement masks: par(sigma^{-1}(t) & ms) = par(t & sigma^{-T} ms)
    for (int w = 0; w < NQ; ++w) {
        unsigned msp = 0;
        for (int i = 0; i < NQ; ++i)
            msp |= (unsigned)(par16(Ci[i] & msIdx[w]) & 1) << i;
        h_pg.ms[w] = msp;
    }
    // combo-part parities of the FINAL pass (measurement runs from registers;
    // cmb8 is pre-shifted, ms is in address space -> compare unshifted)
    for (int w = 0; w < NQ; ++w) {
        unsigned fm = 0;
        for (int i = 0; i < 16; ++i)
            fm |= (unsigned)(par16((h_pg.pass[np - 1].cmb8[i] >> 3) & h_pg.ms[w]) & 1) << i;
        h_pg.fmask[w] = fm;
    }
    // init physical-bit tables: bit_w(sigma^{-1}(a)) = par(a & t_w), with
    // t_w = sigma^{-T}(unit of wire w); IW[j] packs par(R0[j] & t_w) at bit w.
    {
        unsigned tmask[NQ];
        for (int w = 0; w < NQ; ++w) {
            unsigned t = 0;
            for (int i = 0; i < NQ; ++i)
                t |= (unsigned)((Ci[i] >> (NQ - 1 - w)) & 1u) << i;
            tmask[w] = t;
        }
        for (int j = 0; j < 10; ++j) {
            unsigned iw = 0;
            for (int w = 0; w < NQ; ++w)
                iw |= (unsigned)(par16(h_pg.pass[0].R[j] & tmask[w]) & 1) << w;
            h_pg.initIW[j] = iw;
        }
    }

    ParamsG* d_pg = (ParamsG*)d_ws;
    hipMemcpyAsync(d_pg, &h_pg, sizeof(ParamsG), hipMemcpyHostToDevice, stream);
    qsim_kernel<<<dim3(B), dim3(BT), 0, stream>>>(x, qw, wl, bl, out, d_pg, np);
}

// Round 13
// 100.187 us; speedup vs baseline: 1.0255x; 1.0037x over previous
//
#include <hip/hip_runtime.h>
#include <string.h>

#define NQ 14
#define NSTATE (1 << NQ)       // 16384 amplitudes
#define NL 3
#define MAXP 12
#define BT 1024                // old (fallback) kernel block
#define NWAVES (BT / 64)
#define NEX 11                 // extra-gate combo menu size
#define BTS 512                // split kernels block
#define NWS (BTS / 64)
#define HSTATE 8192            // half state (split)

// ============================================================
// Split design: entries {0,1,2} run in kernel1, {3,4,5} in kernel2.
// Per chunk, a functional phi with phi(all chunk masks)=0 exists
// (chunk span rank <= 12 < 14), so each element's state splits into
// two blocks {a: phi(a)=g} that never exchange WITHIN the chunk.
// 2 blocks/element * 128 elements = 256 blocks -> all CUs busy.
// Between kernels the state is exchanged through global memory with
// a GF(2)-chosen slot layout [phi2 | phi1 | mu] so both the k1 write
// and k2 read are fully coalesced. All verified components retained:
// analytic layer-0 init, span-closure extras, LDS param table, fused
// measurement. Fallback: the verified round-10 single kernel.
// ============================================================

// ---------------- shared device helpers ----------------
struct C2x2 { float2 m[2][2]; };

__device__ __forceinline__ float2 cmul(float2 a, float2 b) {
    return make_float2(a.x * b.x - a.y * b.y, a.x * b.y + a.y * b.x);
}
__device__ __forceinline__ float2 cmac(float2 acc, float2 a, float2 b) {
    acc.x = fmaf(a.x, b.x, fmaf(-a.y, b.y, acc.x));
    acc.y = fmaf(a.x, b.y, fmaf(a.y, b.x, acc.y));
    return acc;
}
// PennyLane Rot(phi,theta,omega) = RZ(omega) RY(theta) RZ(phi)
__device__ __forceinline__ C2x2 rot_gate(const float* qp) {
    float phi = qp[0], th = qp[1], om = qp[2];
    float ct, stt; __sincosf(0.5f * th, &stt, &ct);
    float sa, ca; __sincosf(0.5f * (phi + om), &sa, &ca);
    float sb, cb; __sincosf(0.5f * (phi - om), &sb, &cb);
    C2x2 G;
    G.m[0][0] = make_float2(ca * ct, -sa * ct);
    G.m[0][1] = make_float2(-cb * stt, -sb * stt);
    G.m[1][0] = make_float2(cb * stt, -sb * stt);
    G.m[1][1] = make_float2(ca * ct, sa * ct);
    return G;
}
// G := G * RX(ang)
__device__ __forceinline__ C2x2 fuse_rx(C2x2 G, float ang) {
    float sh, ch; __sincosf(0.5f * ang, &sh, &ch);
    float2 c = make_float2(ch, 0.f), is = make_float2(0.f, -sh);
    C2x2 R;
    #pragma unroll
    for (int i = 0; i < 2; ++i) {
        R.m[i][0] = cmac(cmul(G.m[i][0], c), G.m[i][1], is);
        R.m[i][1] = cmac(cmul(G.m[i][1], c), G.m[i][0], is);
    }
    return R;
}

// basis gates: unit combos, orientation = logical bit q; params from LDS psh
#define APPLY_BASIS(PS)                                                     \
    {                                                                       \
        _Pragma("unroll")                                                   \
        for (int q = 0; q < 4; ++q) {                                       \
            if (q < (int)nwr) {                                             \
                const int gi = (int)psh.pass[PS].gidx[q] * 4;               \
                float2 g00 = gbuf[gi + 0], g01 = gbuf[gi + 1];              \
                float2 g10 = gbuf[gi + 2], g11 = gbuf[gi + 3];              \
                _Pragma("unroll")                                           \
                for (int i = 0; i < 16; ++i) {                              \
                    if (!((i >> q) & 1)) {                                  \
                        const int i1 = i | (1 << q);                        \
                        float2 a0 = a[i], a1 = a[i1];                       \
                        float2 n0 = cmac(cmul(g00, a0), g01, a1);           \
                        float2 n1 = cmac(cmul(g10, a0), g11, a1);           \
                        a[i] = n0; a[i1] = n1;                              \
                    }                                                       \
                }                                                           \
            }                                                               \
        }                                                                   \
    }

// ---------------- OLD (fallback) kernel: verbatim round-10 ----------------
struct PassG {
    unsigned cmb8[16];
    unsigned R[10];
    unsigned gidx[4];
    unsigned nw;
    unsigned epm;
    unsigned eg[11];     // sga(14b) | gidx<<16
    unsigned parw[11];
    unsigned pad[2];
};
struct ParamsG {
    PassG pass[MAXP];
    unsigned ms[NQ];
    unsigned fmask[NQ];
    unsigned initIW[10];
};
#define PG_WORDS ((int)(sizeof(ParamsG) / 4))

template<int C>
__device__ __forceinline__ void apply_extra(float2 a[16], const float2* gb,
        unsigned w1, unsigned pw, unsigned rep)
{
    const unsigned sga = w1 & 0x3FFFu;
    const int gi = (int)(w1 >> 16) * 4;
    const unsigned og = __popc(rep & sga) & 1u;
    const unsigned swv = pw ^ (og ? 0xFFFFu : 0u);
    float2 g00 = gb[gi + 0], g01 = gb[gi + 1], g10 = gb[gi + 2], g11 = gb[gi + 3];
    const int LB = C & (-C);
    #pragma unroll
    for (int i = 0; i < 16; ++i) {
        if (!(i & LB)) {
            const int i1 = i ^ C;
            const bool sw = (swv >> i) & 1u;
            float2 x0 = sw ? a[i1] : a[i];
            float2 x1 = sw ? a[i]  : a[i1];
            float2 n0 = cmac(cmul(g00, x0), g01, x1);
            float2 n1 = cmac(cmul(g10, x0), g11, x1);
            a[i]  = sw ? n1 : n0;
            a[i1] = sw ? n0 : n1;
        }
    }
}

#define APPLY_EXTRAS(PS)                                                    \
    {                                                                       \
        if (epm) {                                                          \
            if (epm & (1u<<0))  apply_extra<3> (a, gbuf, psh.pass[PS].eg[0],  psh.pass[PS].parw[0],  rn); \
            if (epm & (1u<<1))  apply_extra<5> (a, gbuf, psh.pass[PS].eg[1],  psh.pass[PS].parw[1],  rn); \
            if (epm & (1u<<2))  apply_extra<6> (a, gbuf, psh.pass[PS].eg[2],  psh.pass[PS].parw[2],  rn); \
            if (epm & (1u<<3))  apply_extra<9> (a, gbuf, psh.pass[PS].eg[3],  psh.pass[PS].parw[3],  rn); \
            if (epm & (1u<<4))  apply_extra<10>(a, gbuf, psh.pass[PS].eg[4],  psh.pass[PS].parw[4],  rn); \
            if (epm & (1u<<5))  apply_extra<12>(a, gbuf, psh.pass[PS].eg[5],  psh.pass[PS].parw[5],  rn); \
            if (epm & (1u<<6))  apply_extra<7> (a, gbuf, psh.pass[PS].eg[6],  psh.pass[PS].parw[6],  rn); \
            if (epm & (1u<<7))  apply_extra<11>(a, gbuf, psh.pass[PS].eg[7],  psh.pass[PS].parw[7],  rn); \
            if (epm & (1u<<8))  apply_extra<13>(a, gbuf, psh.pass[PS].eg[8],  psh.pass[PS].parw[8],  rn); \
            if (epm & (1u<<9))  apply_extra<14>(a, gbuf, psh.pass[PS].eg[9],  psh.pass[PS].parw[9],  rn); \
            if (epm & (1u<<10)) apply_extra<15>(a, gbuf, psh.pass[PS].eg[10], psh.pass[PS].parw[10], rn); \
        }                                                                   \
    }

__global__ __launch_bounds__(BT, 4) void qsim_kernel(
    const float* __restrict__ x, const float* __restrict__ qw,
    const float* __restrict__ wl, const float* __restrict__ bl,
    float* __restrict__ out, const ParamsG* __restrict__ pp, int np)
{
    __shared__ float2 st[NSTATE];
    __shared__ float2 gbuf[NL * NQ * 4];
    __shared__ float2 ubuf[NQ][2];
    __shared__ float red[NWAVES];
    __shared__ __align__(16) ParamsG psh;

    const int tid = threadIdx.x;
    const int b = blockIdx.x;

    {
        const unsigned* srcw = (const unsigned*)pp;
        unsigned* dstw = (unsigned*)&psh;
        for (int i = tid; i < PG_WORDS; i += BT) dstw[i] = srcw[i];
    }
    if (tid < NL * NQ) {
        int l = tid / NQ, w = tid % NQ;
        C2x2 G = rot_gate(qw + tid * 3);
        if (l == 0) {
            G = fuse_rx(G, x[b * NQ + w]);
            ubuf[w][0] = G.m[0][0];
            ubuf[w][1] = G.m[1][0];
        }
        gbuf[tid * 4 + 0] = G.m[0][0];
        gbuf[tid * 4 + 1] = G.m[0][1];
        gbuf[tid * 4 + 2] = G.m[1][0];
        gbuf[tid * 4 + 3] = G.m[1][1];
    }

    char* sb = (char*)st;
    float2 a[16];
    unsigned addr[16];
    unsigned rn;

    __syncthreads();

    {
        unsigned r0 = 0, b0 = 0;
        #pragma unroll
        for (int j = 0; j < 10; ++j) {
            const unsigned sel = (tid >> j) & 1;
            r0 ^= sel ? psh.pass[0].R[j] : 0u;
            b0 ^= sel ? psh.initIW[j] : 0u;
        }
        rn = r0;
        const unsigned rb = rn << 3;
        float2 c = ubuf[0][b0 & 1];
        #pragma unroll
        for (int w = 1; w < 10; ++w)
            c = cmul(c, ubuf[w][(b0 >> w) & 1]);
        a[0] = cmul(c, ubuf[10][0]);
        a[1] = cmul(c, ubuf[10][1]);
        #pragma unroll
        for (int i = 0; i < 2; ++i) {
            a[2 + i] = cmul(a[i], ubuf[11][1]);
            a[i]     = cmul(a[i], ubuf[11][0]);
        }
        #pragma unroll
        for (int i = 0; i < 4; ++i) {
            a[4 + i] = cmul(a[i], ubuf[12][1]);
            a[i]     = cmul(a[i], ubuf[12][0]);
        }
        #pragma unroll
        for (int i = 0; i < 8; ++i) {
            a[8 + i] = cmul(a[i], ubuf[13][1]);
            a[i]     = cmul(a[i], ubuf[13][0]);
        }
        #pragma unroll
        for (int i = 0; i < 16; ++i)
            *(float2*)(sb + (rb ^ psh.pass[0].cmb8[i])) = a[i];
    }

    {
        unsigned rt = 0;
        #pragma unroll
        for (int j = 0; j < 10; ++j)
            rt ^= ((tid >> j) & 1) ? psh.pass[1].R[j] : 0u;
        rn = rt;
    }

    #pragma unroll 1
    for (int ps = 1; ps < np - 1; ++ps) {
        __syncthreads();
        const unsigned rb = rn << 3;
        #pragma unroll
        for (int i = 0; i < 16; ++i) addr[i] = rb ^ psh.pass[ps].cmb8[i];
        #pragma unroll
        for (int i = 0; i < 16; ++i)
            a[i] = *(const float2*)(sb + addr[i]);
        unsigned rt = 0;
        #pragma unroll
        for (int j = 0; j < 10; ++j)
            rt ^= ((tid >> j) & 1) ? psh.pass[ps + 1].R[j] : 0u;
        const unsigned nwr = psh.pass[ps].nw;
        APPLY_BASIS(ps);
        const unsigned epm = psh.pass[ps].epm;
        APPLY_EXTRAS(ps);
        #pragma unroll
        for (int i = 0; i < 16; ++i)
            *(float2*)(sb + addr[i]) = a[i];
        rn = rt;
    }

    float acc = 0.f;
    {
        const int ps = np - 1;
        __syncthreads();
        const unsigned rb = rn << 3;
        #pragma unroll
        for (int i = 0; i < 16; ++i) addr[i] = rb ^ psh.pass[ps].cmb8[i];
        #pragma unroll
        for (int i = 0; i < 16; ++i)
            a[i] = *(const float2*)(sb + addr[i]);
        const unsigned nwr = psh.pass[ps].nw;
        APPLY_BASIS(ps);
        const unsigned epm = psh.pass[ps].epm;
        APPLY_EXTRAS(ps);

        float A[16];
        #pragma unroll
        for (int i = 0; i < 16; ++i) A[i] = 0.f;
        #pragma unroll
        for (int w = 0; w < NQ; ++w) {
            float v = wl[w];
            unsigned p0 = __popc(rn & psh.ms[w]) & 1u;
            float vs = p0 ? -v : v;
            const unsigned fm = psh.fmask[w];
            #pragma unroll
            for (int i = 0; i < 16; ++i)
                A[i] += ((fm >> i) & 1u) ? -vs : vs;
        }
        #pragma unroll
        for (int i = 0; i < 16; ++i)
            acc = fmaf(fmaf(a[i].x, a[i].x, a[i].y * a[i].y), A[i], acc);
    }

    #pragma unroll
    for (int off = 32; off > 0; off >>= 1) acc += __shfl_down(acc, off, 64);
    if ((tid & 63) == 0) red[tid >> 6] = acc;
    __syncthreads();
    if (tid == 0) {
        float s2 = 0.f;
        #pragma unroll
        for (int i = 0; i < NWAVES; ++i) s2 += red[i];
        out[b] = s2 + bl[0];
    }
}

// ---------------- SPLIT kernels ----------------
struct PassK {
    unsigned cmb8[16];   // T-image of combos, <<3
    unsigned R[9];       // T-image of complement (bank pivots first)
    unsigned Ug;         // T-image of the g-direction
    unsigned gidx[4];
    unsigned nw, epm;
    unsigned eg[NEX];    // sga13 | sgc<<13 | gidx<<16
    unsigned parw[NEX];
};
struct ParamsK1 {
    PassK pass[3];       // entry 0 = init
    unsigned initIW[9];  // wire-bit words of raw Rv (reordered with R)
    unsigned initIWg;    // wire-bit word of raw Ug
    unsigned SK[12];     // slot-bit -> LDS byte-offset images
    unsigned SKj, SKg;
    unsigned pad;
};
struct ParamsK2 {
    PassK pass[3];
    unsigned SL[13], SLj;
    unsigned ms[NQ];     // ms13 | msg<<13
    unsigned fmask[NQ];
};
struct ParamsS { ParamsK1 k1; ParamsK2 k2; };

template<int C>
__device__ __forceinline__ void apply_extra_s(float2 a[16], const float2* gb,
        unsigned w1, unsigned pw, unsigned rep, unsigned gbit)
{
    const int gi = (int)(w1 >> 16) * 4;
    const unsigned og = ((unsigned)__popc(rep & (w1 & 0x1FFFu)) ^ ((w1 >> 13) & gbit)) & 1u;
    const unsigned swv = pw ^ (og ? 0xFFFFu : 0u);
    float2 g00 = gb[gi + 0], g01 = gb[gi + 1], g10 = gb[gi + 2], g11 = gb[gi + 3];
    const int LB = C & (-C);
    #pragma unroll
    for (int i = 0; i < 16; ++i) {
        if (!(i & LB)) {
            const int i1 = i ^ C;
            const bool sw = (swv >> i) & 1u;
            float2 x0 = sw ? a[i1] : a[i];
            float2 x1 = sw ? a[i]  : a[i1];
            float2 n0 = cmac(cmul(g00, x0), g01, x1);
            float2 n1 = cmac(cmul(g10, x0), g11, x1);
            a[i]  = sw ? n1 : n0;
            a[i1] = sw ? n0 : n1;
        }
    }
}

#define APPLY_EXTRAS_S(PS, GB)                                              \
    {                                                                       \
        if (epm) {                                                          \
            if (epm & (1u<<0))  apply_extra_s<3> (a, gbuf, psh.pass[PS].eg[0],  psh.pass[PS].parw[0],  rn, GB); \
            if (epm & (1u<<1))  apply_extra_s<5> (a, gbuf, psh.pass[PS].eg[1],  psh.pass[PS].parw[1],  rn, GB); \
            if (epm & (1u<<2))  apply_extra_s<6> (a, gbuf, psh.pass[PS].eg[2],  psh.pass[PS].parw[2],  rn, GB); \
            if (epm & (1u<<3))  apply_extra_s<9> (a, gbuf, psh.pass[PS].eg[3],  psh.pass[PS].parw[3],  rn, GB); \
            if (epm & (1u<<4))  apply_extra_s<10>(a, gbuf, psh.pass[PS].eg[4],  psh.pass[PS].parw[4],  rn, GB); \
            if (epm & (1u<<5))  apply_extra_s<12>(a, gbuf, psh.pass[PS].eg[5],  psh.pass[PS].parw[5],  rn, GB); \
            if (epm & (1u<<6))  apply_extra_s<7> (a, gbuf, psh.pass[PS].eg[6],  psh.pass[PS].parw[6],  rn, GB); \
            if (epm & (1u<<7))  apply_extra_s<11>(a, gbuf, psh.pass[PS].eg[7],  psh.pass[PS].parw[7],  rn, GB); \
            if (epm & (1u<<8))  apply_extra_s<13>(a, gbuf, psh.pass[PS].eg[8],  psh.pass[PS].parw[8],  rn, GB); \
            if (epm & (1u<<9))  apply_extra_s<14>(a, gbuf, psh.pass[PS].eg[9],  psh.pass[PS].parw[9],  rn, GB); \
            if (epm & (1u<<10)) apply_extra_s<15>(a, gbuf, psh.pass[PS].eg[10], psh.pass[PS].parw[10], rn, GB); \
        }                                                                   \
    }

__global__ __launch_bounds__(BTS, 4) void qsim_k1(
    const float* __restrict__ x, const float* __restrict__ qw,
    const ParamsS* __restrict__ pp, float2* __restrict__ stbuf,
    float* __restrict__ out)
{
    __shared__ float2 st[HSTATE];
    __shared__ float2 gbuf[NL * NQ * 4];
    __shared__ float2 ubuf[NQ][2];
    __shared__ ParamsK1 psh;

    const int tid = threadIdx.x;
    const int e = blockIdx.x >> 1, g1 = blockIdx.x & 1;

    {
        const unsigned* s = (const unsigned*)&pp->k1;
        unsigned* d = (unsigned*)&psh;
        for (int i = tid; i < (int)(sizeof(ParamsK1) / 4); i += BTS) d[i] = s[i];
    }
    if (tid < NL * NQ) {
        int l = tid / NQ, w = tid % NQ;
        C2x2 G = rot_gate(qw + tid * 3);
        if (l == 0) {
            G = fuse_rx(G, x[e * NQ + w]);
            ubuf[w][0] = G.m[0][0];
            ubuf[w][1] = G.m[1][0];
        }
        gbuf[tid * 4 + 0] = G.m[0][0];
        gbuf[tid * 4 + 1] = G.m[0][1];
        gbuf[tid * 4 + 2] = G.m[1][0];
        gbuf[tid * 4 + 3] = G.m[1][1];
    }
    char* sb = (char*)st;
    __syncthreads();

    // entry 0: analytic product-state init of this half
    {
        unsigned rn = g1 ? psh.pass[0].Ug : 0u;
        unsigned b0 = g1 ? psh.initIWg : 0u;
        #pragma unroll
        for (int j5 = 0; j5 < 9; ++j5) {
            const unsigned sel = (tid >> j5) & 1u;
            rn ^= sel ? psh.pass[0].R[j5] : 0u;
            b0 ^= sel ? psh.initIW[j5] : 0u;
        }
        const unsigned rb = rn << 3;
        float2 a[16];
        float2 c = ubuf[0][b0 & 1];
        #pragma unroll
        for (int w = 1; w < 10; ++w)
            c = cmul(c, ubuf[w][(b0 >> w) & 1]);
        a[0] = cmul(c, ubuf[10][0]);
        a[1] = cmul(c, ubuf[10][1]);
        #pragma unroll
        for (int i = 0; i < 2; ++i) {
            a[2 + i] = cmul(a[i], ubuf[11][1]);
            a[i]     = cmul(a[i], ubuf[11][0]);
        }
        #pragma unroll
        for (int i = 0; i < 4; ++i) {
            a[4 + i] = cmul(a[i], ubuf[12][1]);
            a[i]     = cmul(a[i], ubuf[12][0]);
        }
        #pragma unroll
        for (int i = 0; i < 8; ++i) {
            a[8 + i] = cmul(a[i], ubuf[13][1]);
            a[i]     = cmul(a[i], ubuf[13][0]);
        }
        #pragma unroll
        for (int i = 0; i < 16; ++i)
            *(float2*)(sb + (rb ^ psh.pass[0].cmb8[i])) = a[i];
    }

    // entries 1,2
    for (int p5 = 1; p5 < 3; ++p5) {
        __syncthreads();
        unsigned rn = g1 ? psh.pass[p5].Ug : 0u;
        #pragma unroll
        for (int j5 = 0; j5 < 9; ++j5)
            rn ^= ((tid >> j5) & 1u) ? psh.pass[p5].R[j5] : 0u;
        const unsigned rb = rn << 3;
        unsigned addr[16];
        #pragma unroll
        for (int i = 0; i < 16; ++i) addr[i] = rb ^ psh.pass[p5].cmb8[i];
        float2 a[16];
        #pragma unroll
        for (int i = 0; i < 16; ++i) a[i] = *(const float2*)(sb + addr[i]);
        const unsigned nwr = psh.pass[p5].nw;
        APPLY_BASIS(p5);
        const unsigned epm = psh.pass[p5].epm;
        APPLY_EXTRAS_S(p5, (unsigned)g1);
        #pragma unroll
        for (int i = 0; i < 16; ++i) *(float2*)(sb + addr[i]) = a[i];
    }
    __syncthreads();

    // gather -> global (coalesced: slot s = i<<9 | tid within each chunk)
    {
        unsigned tb = g1 ? psh.SKg : 0u;
        #pragma unroll
        for (int k = 0; k < 9; ++k)
            tb ^= ((tid >> k) & 1u) ? psh.SK[k] : 0u;
        #pragma unroll
        for (int j2 = 0; j2 < 2; ++j2) {
            const unsigned bb = tb ^ (j2 ? psh.SKj : 0u);
            float2* gdst = stbuf + ((((size_t)e * 2 + j2) * 2 + g1) << 12) + tid;
            #pragma unroll
            for (int i = 0; i < 8; ++i) {
                unsigned la = bb;
                if (i & 1) la ^= psh.SK[9];
                if (i & 2) la ^= psh.SK[10];
                if (i & 4) la ^= psh.SK[11];
                gdst[i * 512] = *(const float2*)(sb + la);
            }
        }
        if (g1 == 0 && tid == 0) out[e] = 0.f;  // replay-safe zero before k2 atomics
    }
}

__global__ __launch_bounds__(BTS, 4) void qsim_k2(
    const float* __restrict__ x, const float* __restrict__ qw,
    const float* __restrict__ wl, const float* __restrict__ bl,
    const ParamsS* __restrict__ pp, const float2* __restrict__ stbuf,
    float* __restrict__ out)
{
    __shared__ float2 st[HSTATE];
    __shared__ float2 gbuf[NL * NQ * 4];
    __shared__ float2 ubuf[NQ][2];
    __shared__ ParamsK2 psh;
    __shared__ float red[NWS];

    const int tid = threadIdx.x;
    const int e = blockIdx.x >> 1, j = blockIdx.x & 1;

    {
        const unsigned* s = (const unsigned*)&pp->k2;
        unsigned* d = (unsigned*)&psh;
        for (int i = tid; i < (int)(sizeof(ParamsK2) / 4); i += BTS) d[i] = s[i];
    }
    if (tid < NL * NQ) {
        int l = tid / NQ, w = tid % NQ;
        C2x2 G = rot_gate(qw + tid * 3);
        if (l == 0) {
            G = fuse_rx(G, x[e * NQ + w]);
            ubuf[w][0] = G.m[0][0];
            ubuf[w][1] = G.m[1][0];
        }
        gbuf[tid * 4 + 0] = G.m[0][0];
        gbuf[tid * 4 + 1] = G.m[0][1];
        gbuf[tid * 4 + 2] = G.m[1][0];
        gbuf[tid * 4 + 3] = G.m[1][1];
    }
    char* sb = (char*)st;
    __syncthreads();

    // scatter in from global (coalesced reads, slot s'' = i<<9 | tid)
    {
        unsigned tb = j ? psh.SLj : 0u;
        #pragma unroll
        for (int k = 0; k < 9; ++k)
            tb ^= ((tid >> k) & 1u) ? psh.SL[k] : 0u;
        const float2* gsrc = stbuf + (((size_t)e * 2 + j) << 13) + tid;
        #pragma unroll
        for (int i = 0; i < 16; ++i) {
            float2 v = gsrc[i * 512];
            unsigned la = tb;
            if (i & 1) la ^= psh.SL[9];
            if (i & 2) la ^= psh.SL[10];
            if (i & 4) la ^= psh.SL[11];
            if (i & 8) la ^= psh.SL[12];
            *(float2*)(sb + la) = v;
        }
    }

    // entries 0,1 (global entries 3,4)
    for (int p5 = 0; p5 < 2; ++p5) {
        __syncthreads();
        unsigned rn = j ? psh.pass[p5].Ug : 0u;
        #pragma unroll
        for (int j5 = 0; j5 < 9; ++j5)
            rn ^= ((tid >> j5) & 1u) ? psh.pass[p5].R[j5] : 0u;
        const unsigned rb = rn << 3;
        unsigned addr[16];
        #pragma unroll
        for (int i = 0; i < 16; ++i) addr[i] = rb ^ psh.pass[p5].cmb8[i];
        float2 a[16];
        #pragma unroll
        for (int i = 0; i < 16; ++i) a[i] = *(const float2*)(sb + addr[i]);
        const unsigned nwr = psh.pass[p5].nw;
        APPLY_BASIS(p5);
        const unsigned epm = psh.pass[p5].epm;
        APPLY_EXTRAS_S(p5, (unsigned)j);
        #pragma unroll
        for (int i = 0; i < 16; ++i) *(float2*)(sb + addr[i]) = a[i];
    }

    // final entry + fused measurement
    float acc = 0.f;
    {
        __syncthreads();
        unsigned rn = j ? psh.pass[2].Ug : 0u;
        #pragma unroll
        for (int j5 = 0; j5 < 9; ++j5)
            rn ^= ((tid >> j5) & 1u) ? psh.pass[2].R[j5] : 0u;
        const unsigned rb = rn << 3;
        unsigned addr[16];
        #pragma unroll
        for (int i = 0; i < 16; ++i) addr[i] = rb ^ psh.pass[2].cmb8[i];
        float2 a[16];
        #pragma unroll
        for (int i = 0; i < 16; ++i) a[i] = *(const float2*)(sb + addr[i]);
        const unsigned nwr = psh.pass[2].nw;
        APPLY_BASIS(2);
        const unsigned epm = psh.pass[2].epm;
        APPLY_EXTRAS_S(2, (unsigned)j);

        float A[16];
        #pragma unroll
        for (int i = 0; i < 16; ++i) A[i] = 0.f;
        #pragma unroll
        for (int w = 0; w < NQ; ++w) {
            float v = wl[w];
            const unsigned msw = psh.ms[w];
            unsigned p0 = ((unsigned)__popc(rn & (msw & 0x1FFFu)) ^ ((msw >> 13) & (unsigned)j)) & 1u;
            float vs = p0 ? -v : v;
            const unsigned fm = psh.fmask[w];
            #pragma unroll
            for (int i = 0; i < 16; ++i)
                A[i] += ((fm >> i) & 1u) ? -vs : vs;
        }
        #pragma unroll
        for (int i = 0; i < 16; ++i)
            acc = fmaf(fmaf(a[i].x, a[i].x, a[i].y * a[i].y), A[i], acc);
    }

    #pragma unroll
    for (int off = 32; off > 0; off >>= 1) acc += __shfl_down(acc, off, 64);
    if ((tid & 63) == 0) red[tid >> 6] = acc;
    __syncthreads();
    if (tid == 0) {
        float s2 = 0.f;
        #pragma unroll
        for (int i = 0; i < NWS; ++i) s2 += red[i];
        atomicAdd(out + e, s2 + (j == 0 ? bl[0] : 0.f));
    }
}

// ---------------- host-side GF(2) helpers ----------------
struct GF2Basis {
    unsigned piv[NQ];
    GF2Basis() { for (int i = 0; i < NQ; ++i) piv[i] = 0; }
    bool insert(unsigned v) {
        for (int bb = NQ - 1; bb >= 0; --bb) {
            if (!((v >> bb) & 1)) continue;
            if (piv[bb]) v ^= piv[bb];
            else { piv[bb] = v; return true; }
        }
        return false;
    }
};

static inline int par16(unsigned v) { return __builtin_parity(v); }
static inline unsigned lcg_next(unsigned& s) { s = s * 1664525u + 1013904223u; return s >> 8; }

static unsigned gf_apply(const unsigned* C, unsigned v) {
    unsigned r = 0;
    while (v) { int j = __builtin_ctz(v); v &= v - 1; r ^= C[j]; }
    return r;
}

static bool gf_invert(const unsigned* C, unsigned* Ci) {
    unsigned rows[NQ], irows[NQ];
    for (int i = 0; i < NQ; ++i) {
        unsigned r = 0;
        for (int j = 0; j < NQ; ++j) r |= ((C[j] >> i) & 1u) << j;
        rows[i] = r; irows[i] = 1u << i;
    }
    for (int c = 0; c < NQ; ++c) {
        int p = -1;
        for (int r = c; r < NQ; ++r) if ((rows[r] >> c) & 1u) { p = r; break; }
        if (p < 0) return false;
        unsigned t = rows[p]; rows[p] = rows[c]; rows[c] = t;
        t = irows[p]; irows[p] = irows[c]; irows[c] = t;
        for (int r = 0; r < NQ; ++r)
            if (r != c && ((rows[r] >> c) & 1u)) { rows[r] ^= rows[c]; irows[r] ^= irows[c]; }
    }
    for (int j = 0; j < NQ; ++j) {
        unsigned col = 0;
        for (int i = 0; i < NQ; ++i) col |= ((irows[i] >> j) & 1u) << i;
        Ci[j] = col;
    }
    return true;
}

static void rows_to_cols(const unsigned* rows, unsigned* cols) {
    for (int j = 0; j < NQ; ++j) {
        unsigned c = 0;
        for (int i = 0; i < NQ; ++i) c |= ((rows[i] >> j) & 1u) << i;
        cols[j] = c;
    }
}

// functional f with par(f & b) = 0 for all b in bas[0..n); 0 if none found
static unsigned gf_nullfunc(const unsigned* bas, int n) {
    unsigned rows[NQ]; int nr = 0;
    for (int i = 0; i < n; ++i) {
        unsigned v = bas[i];
        for (int k = 0; k < nr; ++k) {
            int p = 31 - __builtin_clz(rows[k]);
            if ((v >> p) & 1u) v ^= rows[k];
        }
        if (v) rows[nr++] = v;
    }
    for (int k = 0; k < nr; ++k) {
        int p = 31 - __builtin_clz(rows[k]);
        for (int k2 = 0; k2 < nr; ++k2)
            if (k2 != k && ((rows[k2] >> p) & 1u)) rows[k2] ^= rows[k];
    }
    unsigned pivmask = 0;
    for (int k = 0; k < nr; ++k) pivmask |= 1u << (31 - __builtin_clz(rows[k]));
    for (int f = 0; f < NQ; ++f) {
        if ((pivmask >> f) & 1u) continue;
        unsigned xx = 1u << f;
        for (int k = 0; k < nr; ++k)
            if ((rows[k] >> f) & 1u) xx |= 1u << (31 - __builtin_clz(rows[k]));
        bool ok = true;
        for (int i = 0; i < n && ok; ++i) if (par16(bas[i] & xx)) ok = false;
        if (ok) return xx;
    }
    return 0;
}

static unsigned addr_img(const unsigned* T, unsigned v) {  // 13 functionals
    unsigned r = 0;
    for (int i = 0; i < 13; ++i) r |= (unsigned)(par16(T[i] & v) & 1) << i;
    return r;
}

// ---------------- shared circuit build + packer ----------------
struct RawEntry {
    unsigned mm[4], ss[4];
    unsigned char gidx[4], nw;
    int exgate[NEX];
    unsigned exsel[NEX], exT[NEX];
};
static const int EXC[NEX] = {3, 5, 6, 9, 10, 12, 7, 11, 13, 14, 15};

static int build_and_pack(RawEntry* raw, unsigned* msIdx) {
    int c2s[16]; for (int i = 0; i < 16; ++i) c2s[i] = -1;
    for (int k = 0; k < NEX; ++k) c2s[EXC[k]] = k;

    unsigned gs[NL * NQ], gm[NL * NQ];
    int ggi[NL * NQ];
    unsigned s[NQ], m[NQ];
    for (int w = 0; w < NQ; ++w) s[w] = m[w] = 1u << (NQ - 1 - w);
    int ng = 0;
    for (int l = 0; l < NL; ++l) {
        if (l > 0) {
            for (int w = 0; w < NQ; ++w) {
                gs[ng] = s[w]; gm[ng] = m[w]; ggi[ng] = l * NQ + w; ++ng;
            }
        }
        int r = (l % (NQ - 1)) + 1;
        for (int w = 0; w < NQ; ++w) {
            int c = w, t = (w + r) % NQ;
            s[t] ^= s[c];
            m[c] ^= m[t];
        }
    }
    for (int w = 0; w < NQ; ++w) msIdx[w] = s[w];

    for (int p = 0; p < MAXP; ++p)
        for (int k = 0; k < NEX; ++k) raw[p].exgate[k] = -1;

    // entry 0: init (group aligned to wires 10..13)
    for (int q = 0; q < 4; ++q) {
        raw[0].mm[q] = 1u << (3 - q);
        raw[0].ss[q] = 1u << (3 - q);
        raw[0].gidx[q] = 0;
    }
    raw[0].nw = 0;

    bool used[NL * NQ] = {false};
    int np = 1, remaining = ng;
    while (remaining > 0 && np < MAXP) {
        unsigned pss[4], pmm[4];
        int pgi[4], nw = 0;
        GF2Basis gf;
        for (int g = 0; g < ng && nw < 4; ++g) {
            if (used[g]) continue;
            bool ok = true;
            for (int k = 0; k < nw && ok; ++k)
                if (par16(gs[g] & pmm[k]) || par16(pss[k] & gm[g])) ok = false;
            for (int h = 0; h < g && ok; ++h)
                if (!used[h] && (par16(gs[g] & gm[h]) || par16(gs[h] & gm[g]))) ok = false;
            if (!ok) continue;
            GF2Basis trial = gf;
            if (!trial.insert(gm[g])) continue;
            gf = trial;
            pss[nw] = gs[g]; pmm[nw] = gm[g]; pgi[nw] = g; ++nw;
            used[g] = true; --remaining;
        }
        unsigned mm[4], ss[4];
        for (int i = 0; i < nw; ++i) { mm[i] = pmm[i]; ss[i] = pss[i]; }
        for (int i = nw; i < 4; ++i) {
            unsigned cand = 0;
            for (int t = 0; t < NQ; ++t)
                if (gf.insert(1u << t)) { cand = 1u << t; break; }
            for (int jq = 0; jq < nw; ++jq)
                if (par16(cand & ss[jq])) cand ^= mm[jq];
            mm[i] = cand; ss[i] = 0;
        }
        for (int q = 0; q < 4; ++q) { raw[np].mm[q] = mm[q]; raw[np].ss[q] = ss[q]; }
        for (int q = 0; q < 4; ++q)
            raw[np].gidx[q] = (unsigned char)(q < nw ? ggi[pgi[q]] : 0);
        raw[np].nw = (unsigned char)nw;

        // extras sweep
        {
            int exCirc[NEX]; int nExtra = 0;
            for (int g = 0; g < ng; ++g) {
                if (used[g]) continue;
                int c = -1;
                for (int t2 = 3; t2 < 16; ++t2) {
                    if (__builtin_popcount((unsigned)t2) < 2) continue;
                    unsigned xr = 0;
                    for (int jq = 0; jq < 4; ++jq) if ((t2 >> jq) & 1) xr ^= mm[jq];
                    if (xr == gm[g]) { c = t2; break; }
                }
                if (c < 0) continue;
                int slot = c2s[c];
                if (slot < 0 || raw[np].exgate[slot] >= 0) continue;
                unsigned T = 0;
                for (int jq = 0; jq < 4; ++jq)
                    T |= (unsigned)(par16(mm[jq] & gs[g]) & 1) << jq;
                {
                    int sp = 0;
                    for (int jq = 0; jq < 4; ++jq) if ((c >> jq) & 1) sp ^= (T >> jq) & 1;
                    if (!sp) continue;
                }
                bool ok = true;
                for (int e2 = 0; e2 < nExtra && ok; ++e2) {
                    int h = exCirc[e2];
                    if (par16(gs[g] & gm[h]) || par16(gs[h] & gm[g])) ok = false;
                }
                for (int kk = 0; kk < nw && ok; ++kk) {
                    int h = pgi[kk];
                    if (h > g && (par16(gs[g] & gm[h]) || par16(gs[h] & gm[g]))) ok = false;
                }
                for (int h = 0; h < g && ok; ++h)
                    if (!used[h] && (par16(gs[g] & gm[h]) || par16(gs[h] & gm[g]))) ok = false;
                if (!ok) continue;
                raw[np].exgate[slot] = ggi[g];
                raw[np].exsel[slot] = gs[g];
                raw[np].exT[slot] = T;
                exCirc[nExtra++] = g;
                used[g] = true; --remaining;
            }
        }
        ++np;
    }
    return np;
}

// ---------------- old-path emit (round-10 semantics) ----------------
static void old_emit(const RawEntry* raw, int np, const unsigned* msIdx,
                     ParamsG& h_pg, unsigned seed) {
    unsigned rvA[MAXP][10];
    for (int p = 0; p < np; ++p) {
        GF2Basis gf;
        for (int q = 0; q < 4; ++q) gf.insert(raw[p].mm[q]);
        int nR = 0;
        for (int t = 0; t < NQ && nR < 10; ++t) {
            if (gf.insert(1u << t)) {
                unsigned v = 1u << t;
                for (int q = 0; q < 4; ++q)
                    if (par16(v & raw[p].ss[q])) v ^= raw[p].mm[q];
                rvA[p][nR++] = v;
            }
        }
    }
    unsigned Cm[NQ], Ci[NQ];
    bool found = false;
    for (int tries = 0; tries < 5000 && !found; ++tries) {
        for (int j = 0; j < NQ; ++j) Cm[j] = lcg_next(seed) & (NSTATE - 1);
        if (!gf_invert(Cm, Ci)) continue;
        found = true;
        for (int p = 0; p < np && found; ++p) {
            unsigned piv[4] = {0, 0, 0, 0}; int npv = 0;
            for (int i = 0; i < 10; ++i) {
                unsigned w2 = gf_apply(Cm, rvA[p][i]);
                for (int bb = 0; bb < 4; ++bb)
                    if (((w2 >> bb) & 1u) && piv[bb]) w2 ^= piv[bb];
                if ((w2 & 15u) && npv < 4) { piv[__builtin_ctz(w2 & 15u)] = w2; ++npv; }
            }
            if (npv < 4) found = false;
        }
    }
    if (!found) { for (int j = 0; j < NQ; ++j) Cm[j] = 1u << j; gf_invert(Cm, Ci); }

    memset(&h_pg, 0, sizeof(h_pg));
    for (int p = 0; p < np; ++p) {
        unsigned u[10];
        for (int i = 0; i < 10; ++i) u[i] = gf_apply(Cm, rvA[p][i]);
        unsigned piv[4] = {0, 0, 0, 0};
        int ord[10], npv = 0, rest[10], nrest = 0;
        for (int i = 0; i < 10; ++i) {
            unsigned w2 = u[i];
            for (int bb = 0; bb < 4; ++bb)
                if (((w2 >> bb) & 1u) && piv[bb]) w2 ^= piv[bb];
            if ((w2 & 15u) && npv < 4) { piv[__builtin_ctz(w2 & 15u)] = w2; ord[npv++] = i; }
            else rest[nrest++] = i;
        }
        int kk = 0;
        for (int i = 0; i < npv; ++i) h_pg.pass[p].R[kk++] = u[ord[i]];
        for (int i = 0; i < nrest; ++i) h_pg.pass[p].R[kk++] = u[rest[i]];
        for (int idx = 0; idx < 16; ++idx) {
            unsigned c = 0;
            for (int q = 0; q < 4; ++q) if ((idx >> q) & 1) c ^= raw[p].mm[q];
            h_pg.pass[p].cmb8[idx] = gf_apply(Cm, c) << 3;
        }
        for (int q = 0; q < 4; ++q) h_pg.pass[p].gidx[q] = raw[p].gidx[q];
        h_pg.pass[p].nw = raw[p].nw;
        unsigned epm = 0;
        for (int k = 0; k < NEX; ++k) {
            if (raw[p].exgate[k] < 0) continue;
            epm |= 1u << k;
            unsigned sga = 0;
            for (int i = 0; i < NQ; ++i)
                sga |= (unsigned)(par16(Ci[i] & raw[p].exsel[k]) & 1) << i;
            h_pg.pass[p].eg[k] = sga | ((unsigned)raw[p].exgate[k] << 16);
            unsigned T = raw[p].exT[k], pw = 0;
            for (int i = 0; i < 16; ++i)
                pw |= (unsigned)(__builtin_popcount(i & T) & 1) << i;
            h_pg.pass[p].parw[k] = pw;
        }
        h_pg.pass[p].epm = epm;
    }
    for (int w = 0; w < NQ; ++w) {
        unsigned msp = 0;
        for (int i = 0; i < NQ; ++i)
            msp |= (unsigned)(par16(Ci[i] & msIdx[w]) & 1) << i;
        h_pg.ms[w] = msp;
    }
    for (int w = 0; w < NQ; ++w) {
        unsigned fm = 0;
        for (int i = 0; i < 16; ++i)
            fm |= (unsigned)(par16((h_pg.pass[np - 1].cmb8[i] >> 3) & h_pg.ms[w]) & 1) << i;
        h_pg.fmask[w] = fm;
    }
    {
        unsigned tmask[NQ];
        for (int w = 0; w < NQ; ++w) {
            unsigned t = 0;
            for (int i = 0; i < NQ; ++i)
                t |= (unsigned)((Ci[i] >> (NQ - 1 - w)) & 1u) << i;
            tmask[w] = t;
        }
        for (int j = 0; j < 10; ++j) {
            unsigned iw = 0;
            for (int w = 0; w < NQ; ++w)
                iw |= (unsigned)(par16(h_pg.pass[0].R[j] & tmask[w]) & 1) << w;
            h_pg.initIW[j] = iw;
        }
    }
}

// ---------------- split-path emit ----------------
static bool try_split(const RawEntry* raw, int np, const unsigned* msIdx,
                      ParamsS& SP, unsigned seed) {
    if (np != 6) return false;
    for (int p = 1; p < 6; ++p) if (raw[p].nw != 4) return false;
    memset(&SP, 0, sizeof(SP));

    unsigned phi[2];
    for (int c = 0; c < 2; ++c) {
        unsigned bas[12]; int nb = 0;
        for (int p = c * 3; p < c * 3 + 3; ++p)
            for (int q = 0; q < 4; ++q) bas[nb++] = raw[p].mm[q];
        phi[c] = gf_nullfunc(bas, nb);
        if (!phi[c]) return false;
    }
    // slot map rows: 0..11 = mu, 12 = phi1 (g1), 13 = phi2 (j)
    unsigned rows2[NQ];
    {
        GF2Basis rb;
        if (!rb.insert(phi[1])) return false;
        if (!rb.insert(phi[0])) return false;
        int nmu = 0;
        for (int t = 0; t < NQ && nmu < 12; ++t)
            if (rb.insert(1u << t)) rows2[nmu++] = 1u << t;
        if (nmu != 12) return false;
        rows2[12] = phi[0];
        rows2[13] = phi[1];
    }
    unsigned colsM[NQ], Ci2[NQ];
    rows_to_cols(rows2, colsM);
    if (!gf_invert(colsM, Ci2)) return false;
    // Ci2[k] k<12 = Vmu_k, Ci2[12] = G, Ci2[13] = J  (amp = XOR over slot bits)

    for (int k = 0; k < 2; ++k) {
        unsigned ph = phi[k];
        int p0e = k * 3;
        int pivbit = __builtin_ctz(ph);
        unsigned kb[13]; int nkb = 0;
        for (int t = 0; t < NQ; ++t) {
            if (t == pivbit) continue;
            unsigned v = 1u << t;
            if ((ph >> t) & 1u) v ^= 1u << pivbit;
            kb[nkb++] = v;
        }
        unsigned RvAll[3][9], UgAll[3];
        for (int pe = 0; pe < 3; ++pe) {
            const RawEntry& re = raw[p0e + pe];
            for (int q = 0; q < 4; ++q) if (par16(ph & re.mm[q])) return false;
            GF2Basis gfb;
            for (int q = 0; q < 4; ++q) if (!gfb.insert(re.mm[q])) return false;
            int nR = 0;
            for (int i = 0; i < 13 && nR < 9; ++i) {
                unsigned v = kb[i];
                if (gfb.insert(v)) {
                    for (int q = 0; q < 4; ++q)
                        if (par16(v & re.ss[q])) v ^= re.mm[q];
                    RvAll[pe][nR++] = v;
                }
            }
            if (nR != 9) return false;
            unsigned ug = 1u << pivbit;
            for (int q = 0; q < 4; ++q)
                if (par16(ug & re.ss[q])) ug ^= re.mm[q];
            UgAll[pe] = ug;
        }
        // T search: [T;phi] invertible + bank rank-4 per entry
        unsigned T[13], Vt[NQ], Wt = 0;
        bool found = false;
        for (int tries = 0; tries < 20000 && !found; ++tries) {
            for (int i = 0; i < 13; ++i) T[i] = lcg_next(seed) & (NSTATE - 1);
            unsigned mrows[NQ], cm[NQ], ci[NQ];
            for (int i = 0; i < 13; ++i) mrows[i] = T[i];
            mrows[13] = ph;
            rows_to_cols(mrows, cm);
            if (!gf_invert(cm, ci)) continue;
            bool ok = true;
            for (int pe = 0; pe < 3 && ok; ++pe) {
                unsigned piv[4] = {0, 0, 0, 0}; int npv = 0;
                for (int i = 0; i < 9; ++i) {
                    unsigned w2 = addr_img(T, RvAll[pe][i]);
                    for (int bb = 0; bb < 4; ++bb)
                        if (((w2 >> bb) & 1u) && piv[bb]) w2 ^= piv[bb];
                    if ((w2 & 15u) && npv < 4) { piv[__builtin_ctz(w2 & 15u)] = w2; ++npv; }
                }
                if (npv < 4) ok = false;
            }
            if (!ok) continue;
            found = true;
            for (int i = 0; i < NQ; ++i) Vt[i] = ci[i];
            Wt = ci[13];
        }
        if (!found) return false;

        PassK* PK = (k == 0) ? SP.k1.pass : SP.k2.pass;
        int ord0[9];  // entry-0 reorder (for initIW)
        for (int pe = 0; pe < 3; ++pe) {
            const RawEntry& re = raw[p0e + pe];
            PassK& P = PK[pe];
            unsigned img[9];
            for (int i = 0; i < 9; ++i) img[i] = addr_img(T, RvAll[pe][i]);
            unsigned piv[4] = {0, 0, 0, 0};
            int ord[9], npv = 0, rest[9], nrest = 0;
            for (int i = 0; i < 9; ++i) {
                unsigned w2 = img[i];
                for (int bb = 0; bb < 4; ++bb)
                    if (((w2 >> bb) & 1u) && piv[bb]) w2 ^= piv[bb];
                if ((w2 & 15u) && npv < 4) { piv[__builtin_ctz(w2 & 15u)] = w2; ord[npv++] = i; }
                else rest[nrest++] = i;
            }
            int kk = 0;
            for (int i = 0; i < npv; ++i)  { if (pe == 0) ord0[kk] = ord[i];  P.R[kk] = img[ord[i]];  ++kk; }
            for (int i = 0; i < nrest; ++i){ if (pe == 0) ord0[kk] = rest[i]; P.R[kk] = img[rest[i]]; ++kk; }
            P.Ug = addr_img(T, UgAll[pe]);
            for (int idx = 0; idx < 16; ++idx) {
                unsigned c = 0;
                for (int q = 0; q < 4; ++q) if ((idx >> q) & 1) c ^= re.mm[q];
                P.cmb8[idx] = addr_img(T, c) << 3;
            }
            for (int q = 0; q < 4; ++q) P.gidx[q] = re.gidx[q];
            P.nw = re.nw;
            unsigned epm = 0;
            for (int sl = 0; sl < NEX; ++sl) {
                if (re.exgate[sl] < 0) continue;
                epm |= 1u << sl;
                unsigned sga = 0;
                for (int i = 0; i < 13; ++i)
                    sga |= (unsigned)(par16(Vt[i] & re.exsel[sl]) & 1) << i;
                unsigned sgc = (unsigned)(par16(Wt & re.exsel[sl]) & 1);
                P.eg[sl] = sga | (sgc << 13) | ((unsigned)re.exgate[sl] << 16);
                unsigned Tq = re.exT[sl], pw = 0;
                for (int i = 0; i < 16; ++i)
                    pw |= (unsigned)(__builtin_popcount(i & Tq) & 1) << i;
                P.parw[sl] = pw;
            }
            P.epm = epm;
        }
        if (k == 0) {
            for (int jj = 0; jj < 9; ++jj) {
                unsigned v = RvAll[0][ord0[jj]], iw = 0;
                for (int w = 0; w < NQ; ++w)
                    iw |= ((v >> (NQ - 1 - w)) & 1u) << w;
                SP.k1.initIW[jj] = iw;
            }
            {
                unsigned v = UgAll[0], iw = 0;
                for (int w = 0; w < NQ; ++w)
                    iw |= ((v >> (NQ - 1 - w)) & 1u) << w;
                SP.k1.initIWg = iw;
            }
            for (int i = 0; i < 12; ++i) SP.k1.SK[i] = addr_img(T, Ci2[i]) << 3;
            SP.k1.SKg = addr_img(T, Ci2[12]) << 3;
            SP.k1.SKj = addr_img(T, Ci2[13]) << 3;
        } else {
            for (int i = 0; i < 12; ++i) SP.k2.SL[i] = addr_img(T, Ci2[i]) << 3;
            SP.k2.SL[12] = addr_img(T, Ci2[12]) << 3;
            SP.k2.SLj    = addr_img(T, Ci2[13]) << 3;
            for (int w = 0; w < NQ; ++w) {
                unsigned m13 = 0;
                for (int i = 0; i < 13; ++i)
                    m13 |= (unsigned)(par16(Vt[i] & msIdx[w]) & 1) << i;
                unsigned mg = (unsigned)(par16(Wt & msIdx[w]) & 1);
                SP.k2.ms[w] = m13 | (mg << 13);
            }
            for (int w = 0; w < NQ; ++w) {
                unsigned fm = 0;
                for (int i = 0; i < 16; ++i) {
                    unsigned c = 0;
                    for (int q = 0; q < 4; ++q) if ((i >> q) & 1) c ^= raw[5].mm[q];
                    fm |= (unsigned)(par16(c & msIdx[w]) & 1) << i;
                }
                SP.k2.fmask[w] = fm;
            }
        }
    }
    return true;
}

// ---------------- launch ----------------
extern "C" void kernel_launch(void* const* d_in, const int* in_sizes, int n_in,
                              void* d_out, int out_size, void* d_ws, size_t ws_size,
                              hipStream_t stream) {
    const float* x  = (const float*)d_in[0];
    const float* qw = (const float*)d_in[1];
    const float* wl = (const float*)d_in[2];
    const float* bl = (const float*)d_in[3];
    float* out = (float*)d_out;

    const int B = in_sizes[0] / NQ;

    static RawEntry raw[MAXP];
    unsigned msIdx[NQ];
    int np = build_and_pack(raw, msIdx);

    static ParamsS h_sp;
    static ParamsG h_pg;
    const size_t stoff = 4096;
    const size_t need = stoff + (size_t)B * NSTATE * sizeof(float2);

    bool use_split = (ws_size >= need) &&
                     try_split(raw, np, msIdx, h_sp, 0xC0FFEE13u);

    if (use_split) {
        hipMemcpyAsync(d_ws, &h_sp, sizeof(ParamsS), hipMemcpyHostToDevice, stream);
        float2* stb = (float2*)((char*)d_ws + stoff);
        qsim_k1<<<dim3(2 * B), dim3(BTS), 0, stream>>>(
            x, qw, (const ParamsS*)d_ws, stb, out);
        qsim_k2<<<dim3(2 * B), dim3(BTS), 0, stream>>>(
            x, qw, wl, bl, (const ParamsS*)d_ws, stb, out);
    } else {
        old_emit(raw, np, msIdx, h_pg, 0x9E3779B9u);
        hipMemcpyAsync(d_ws, &h_pg, sizeof(ParamsG), hipMemcpyHostToDevice, stream);
        qsim_kernel<<<dim3(B), dim3(BT), 0, stream>>>(
            x, qw, wl, bl, out, (const ParamsG*)d_ws, np);
    }
}